// Round 1
// baseline (2312.104 us; speedup 1.0000x reference)
//
#include <hip/hip_runtime.h>

#define NA 50000
#define NB 20000
#define NE0 600000
#define NE1 300000
#define NE2 300000
#define DD 128
#define DEG_TOT (4 * NA + 2 * NB)

typedef short bf16x8 __attribute__((ext_vector_type(8)));
typedef float f32x4 __attribute__((ext_vector_type(4)));

__device__ __forceinline__ unsigned short f2bf(float f) {
    union { float f; unsigned int u; } v; v.f = f;
    unsigned int r = v.u + 0x7fffu + ((v.u >> 16) & 1u);   // round-to-nearest-even
    return (unsigned short)(r >> 16);
}
__device__ __forceinline__ float bf2f(unsigned short u) {
    union { float f; unsigned int u; } v; v.u = ((unsigned int)u) << 16;
    return v.f;
}

// ---- degree counting: one pass over all three edge lists --------------------
__global__ __launch_bounds__(256) void deg_kernel(
    const int* __restrict__ s0, const int* __restrict__ d0,
    const int* __restrict__ s1, const int* __restrict__ d1,
    const int* __restrict__ s2, const int* __restrict__ d2,
    float* __restrict__ deg)
{
    int i = blockIdx.x * 256 + threadIdx.x;
    int stride = gridDim.x * 256;
    for (int e = i; e < NE0; e += stride) {
        atomicAdd(deg + s0[e], 1.f);                 // dout0 [NA]
        atomicAdd(deg + NA + d0[e], 1.f);            // din0  [NA]
    }
    for (int e = i; e < NE1; e += stride) {
        atomicAdd(deg + 2 * NA + s1[e], 1.f);        // dout1 [NA]
        atomicAdd(deg + 3 * NA + d1[e], 1.f);        // din1  [NB]
    }
    for (int e = i; e < NE2; e += stride) {
        atomicAdd(deg + 3 * NA + NB + s2[e], 1.f);   // dout2 [NB]
        atomicAdd(deg + 3 * NA + 2 * NB + d2[e], 1.f); // din2 [NA]
    }
}

__global__ __launch_bounds__(256) void rsqrt_kernel(float* __restrict__ deg) {
    int i = blockIdx.x * 256 + threadIdx.x;
    if (i < DEG_TOT) deg[i] = rsqrtf(fmaxf(deg[i], 1.f));
}

// ---- fp32 -> bf16 feature conversion ---------------------------------------
__global__ __launch_bounds__(256) void convert_kernel(
    const float* __restrict__ hA, const float* __restrict__ hB,
    unsigned short* __restrict__ xA, unsigned short* __restrict__ xB)
{
    int i = blockIdx.x * 256 + threadIdx.x;   // index of 4-element group
    const int nA4 = NA * DD / 4;
    const int nB4 = NB * DD / 4;
    if (i < nA4) {
        float4 v = ((const float4*)hA)[i];
        ushort4 o; o.x = f2bf(v.x); o.y = f2bf(v.y); o.z = f2bf(v.z); o.w = f2bf(v.w);
        ((ushort4*)xA)[i] = o;
    } else if (i < nA4 + nB4) {
        int j = i - nA4;
        float4 v = ((const float4*)hB)[j];
        ushort4 o; o.x = f2bf(v.x); o.y = f2bf(v.y); o.z = f2bf(v.z); o.w = f2bf(v.w);
        ((ushort4*)xB)[j] = o;
    }
}

// ---- W -> bf16 W^T (Wt[n*128+k] = W[k*128+n]) for B-fragment loads ----------
__global__ __launch_bounds__(256) void wt_kernel(
    const float* __restrict__ W0, const float* __restrict__ W1,
    const float* __restrict__ W2, unsigned short* __restrict__ Wt)
{
    int i = blockIdx.x * 256 + threadIdx.x;
    if (i >= 3 * DD * DD) return;
    int w = i >> 14, r = i & (DD * DD - 1);
    int c = r >> 7, k = r & (DD - 1);
    const float* W = (w == 0) ? W0 : ((w == 1) ? W1 : W2);
    Wt[i] = f2bf(W[k * DD + c]);
}

// ---- MFMA GEMM: M[r][c] = bf16( (X @ W)[r][c] * rs_out[r] ) -----------------
// wave = 16 rows; block = 4 waves = 64 rows; K=128 as 4 k-steps of 32.
__global__ __launch_bounds__(256) void mfma_gemm(
    const unsigned short* __restrict__ X,   // [nrows,128] bf16
    const unsigned short* __restrict__ Wt,  // [128 n][128 k] bf16 (W transposed)
    const float* __restrict__ rs,           // deg_out^-1/2 per row
    unsigned short* __restrict__ M,         // [nrows,128] bf16 out
    int nrows)
{
    int wid  = threadIdx.x >> 6;
    int lane = threadIdx.x & 63;
    int quad = lane >> 4;
    int l16  = lane & 15;
    int base = blockIdx.x * 64 + wid * 16;
    if (base >= nrows) return;

    int arow = base + l16;
    if (arow >= nrows) arow = nrows - 1;    // clamped rows only pollute discarded out-rows
    bf16x8 a[4];
    #pragma unroll
    for (int kk = 0; kk < 4; ++kk)
        a[kk] = *(const bf16x8*)(X + (size_t)arow * DD + kk * 32 + quad * 8);

    #pragma unroll
    for (int ct = 0; ct < 8; ++ct) {
        f32x4 acc = {0.f, 0.f, 0.f, 0.f};
        const unsigned short* wp = Wt + (size_t)(ct * 16 + l16) * DD + quad * 8;
        #pragma unroll
        for (int kk = 0; kk < 4; ++kk) {
            bf16x8 b = *(const bf16x8*)(wp + kk * 32);
            acc = __builtin_amdgcn_mfma_f32_16x16x32_bf16(a[kk], b, acc, 0, 0, 0);
        }
        int orow0 = base + quad * 4;
        #pragma unroll
        for (int r = 0; r < 4; ++r) {
            int orow = orow0 + r;
            if (orow < nrows)
                M[(size_t)orow * DD + ct * 16 + l16] = f2bf(acc[r] * rs[orow]);
        }
    }
}

// ---- init output with per-ntype bias sums (also clears 0xAA poison) ---------
__global__ __launch_bounds__(256) void bias_kernel(
    const float* __restrict__ b0, const float* __restrict__ b1,
    const float* __restrict__ b2, float* __restrict__ out)
{
    int i = blockIdx.x * 256 + threadIdx.x;
    if (i < NA * DD) out[i] = b0[i & (DD - 1)] + b2[i & (DD - 1)];
    else if (i < NA * DD + NB * DD) out[i] = b1[i & (DD - 1)];
}

// ---- edge scatter: out[dst] += m[src] * din^-1/2[dst]  (32 thr/edge) --------
__global__ __launch_bounds__(256) void scatter_kernel(
    const int* __restrict__ src, const int* __restrict__ dst,
    const unsigned short* __restrict__ M, const float* __restrict__ rdin,
    float* __restrict__ out, int nedges)
{
    int gtid = blockIdx.x * 256 + threadIdx.x;
    int e = gtid >> 5;
    if (e >= nedges) return;
    int lane = gtid & 31;
    int s = src[e], t = dst[e];
    float sc = rdin[t];
    ushort4 mv = *(const ushort4*)(M + (size_t)s * DD + lane * 4);
    float* o = out + (size_t)t * DD + lane * 4;
    atomicAdd(o + 0, bf2f(mv.x) * sc);
    atomicAdd(o + 1, bf2f(mv.y) * sc);
    atomicAdd(o + 2, bf2f(mv.z) * sc);
    atomicAdd(o + 3, bf2f(mv.w) * sc);
}

extern "C" void kernel_launch(void* const* d_in, const int* in_sizes, int n_in,
                              void* d_out, int out_size, void* d_ws, size_t ws_size,
                              hipStream_t stream) {
    const float* hA = (const float*)d_in[0];
    const float* hB = (const float*)d_in[1];
    const float* W0 = (const float*)d_in[2];
    const float* b0 = (const float*)d_in[3];
    const float* W1 = (const float*)d_in[4];
    const float* b1 = (const float*)d_in[5];
    const float* W2 = (const float*)d_in[6];
    const float* b2 = (const float*)d_in[7];
    const int* s0 = (const int*)d_in[8];
    const int* d0 = (const int*)d_in[9];
    const int* s1 = (const int*)d_in[10];
    const int* d1 = (const int*)d_in[11];
    const int* s2 = (const int*)d_in[12];
    const int* d2 = (const int*)d_in[13];
    float* out = (float*)d_out;
    char* ws = (char*)d_ws;

    // ws layout (bytes, 16B-aligned):
    unsigned short* mA0 = (unsigned short*)(ws + 0);          // NA*128 bf16 = 12.8 MB
    unsigned short* mA1 = (unsigned short*)(ws + 12800000);   // 12.8 MB
    unsigned short* mB2 = (unsigned short*)(ws + 25600000);   // 5.12 MB
    unsigned short* xA  = (unsigned short*)(ws + 30720000);   // 12.8 MB
    unsigned short* xB  = (unsigned short*)(ws + 43520000);   // 5.12 MB
    unsigned short* Wt  = (unsigned short*)(ws + 48640000);   // 3*32 KB
    float* deg          = (float*)(ws + 48738304);            // 240000 floats

    hipMemsetAsync(deg, 0, DEG_TOT * sizeof(float), stream);
    deg_kernel<<<2048, 256, 0, stream>>>(s0, d0, s1, d1, s2, d2, deg);
    rsqrt_kernel<<<(DEG_TOT + 255) / 256, 256, 0, stream>>>(deg);

    convert_kernel<<<((NA * DD + NB * DD) / 4 + 255) / 256, 256, 0, stream>>>(hA, hB, xA, xB);
    wt_kernel<<<(3 * DD * DD + 255) / 256, 256, 0, stream>>>(W0, W1, W2, Wt);

    // m = (X @ W) * deg_out^{-1/2}
    mfma_gemm<<<(NA + 63) / 64, 256, 0, stream>>>(xA, Wt,            deg,                mA0, NA);
    mfma_gemm<<<(NA + 63) / 64, 256, 0, stream>>>(xA, Wt + 16384,    deg + 2 * NA,       mA1, NA);
    mfma_gemm<<<(NB + 63) / 64, 256, 0, stream>>>(xB, Wt + 32768,    deg + 3 * NA + NB,  mB2, NB);

    bias_kernel<<<(NA * DD + NB * DD + 255) / 256, 256, 0, stream>>>(b0, b1, b2, out);

    // out[dst] += m[src] * deg_in^{-1/2}[dst]
    scatter_kernel<<<(size_t)NE0 * 32 / 256, 256, 0, stream>>>(s0, d0, mA0, deg + NA,              out,           NE0);
    scatter_kernel<<<(size_t)NE1 * 32 / 256, 256, 0, stream>>>(s1, d1, mA1, deg + 3 * NA,          out + NA * DD, NE1);
    scatter_kernel<<<(size_t)NE2 * 32 / 256, 256, 0, stream>>>(s2, d2, mB2, deg + 3 * NA + 2 * NB, out,           NE2);
}

// Round 2
// 449.803 us; speedup vs baseline: 5.1403x; 5.1403x over previous
//
#include <hip/hip_runtime.h>

#define NA 50000
#define NB 20000
#define NE0 600000
#define NE1 300000
#define NE2 300000
#define DD 128
#define DEG_TOT (4 * NA + 2 * NB)

typedef short bf16x8 __attribute__((ext_vector_type(8)));
typedef float f32x4 __attribute__((ext_vector_type(4)));

__device__ __forceinline__ unsigned short f2bf(float f) {
    union { float f; unsigned int u; } v; v.f = f;
    unsigned int r = v.u + 0x7fffu + ((v.u >> 16) & 1u);   // RNE
    return (unsigned short)(r >> 16);
}
__device__ __forceinline__ float bf2f(unsigned int u16) {
    union { float f; unsigned int u; } v; v.u = u16 << 16;
    return v.f;
}

// ---- integer degree counting (one pass, all relations) ----------------------
// layout in ideg: [dout0 NA][din0 NA][dout1 NA][din1 NB][dout2 NB][din2 NA]
__global__ __launch_bounds__(256) void deg_kernel(
    const int* __restrict__ s0, const int* __restrict__ d0,
    const int* __restrict__ s1, const int* __restrict__ d1,
    const int* __restrict__ s2, const int* __restrict__ d2,
    int* __restrict__ ideg)
{
    int i = blockIdx.x * 256 + threadIdx.x;
    int stride = gridDim.x * 256;
    for (int e = i; e < NE0; e += stride) {
        atomicAdd(ideg + s0[e], 1);
        atomicAdd(ideg + NA + d0[e], 1);
    }
    for (int e = i; e < NE1; e += stride) {
        atomicAdd(ideg + 2 * NA + s1[e], 1);
        atomicAdd(ideg + 3 * NA + d1[e], 1);
    }
    for (int e = i; e < NE2; e += stride) {
        atomicAdd(ideg + 3 * NA + NB + s2[e], 1);
        atomicAdd(ideg + 3 * NA + 2 * NB + d2[e], 1);
    }
}

__global__ __launch_bounds__(256) void rsqrt_kernel(
    const int* __restrict__ ideg, float* __restrict__ rdeg)
{
    int i = blockIdx.x * 256 + threadIdx.x;
    if (i < DEG_TOT) rdeg[i] = rsqrtf(fmaxf((float)ideg[i], 1.f));
}

// ---- 3-kernel exclusive scan (1024 elems / block) ---------------------------
__global__ __launch_bounds__(256) void scan_reduce(
    const int* __restrict__ deg, int* __restrict__ part, int n)
{
    __shared__ int lds[256];
    int b = blockIdx.x, t = threadIdx.x;
    int s = 0;
    int base = b * 1024 + t * 4;
    #pragma unroll
    for (int k = 0; k < 4; ++k) { int i = base + k; if (i < n) s += deg[i]; }
    lds[t] = s; __syncthreads();
    for (int off = 128; off > 0; off >>= 1) {
        if (t < off) lds[t] += lds[t + off];
        __syncthreads();
    }
    if (t == 0) part[b] = lds[0];
}

__global__ void scan_spine(int* __restrict__ part, int n) {
    if (threadIdx.x == 0 && blockIdx.x == 0) {
        int run = 0;
        for (int i = 0; i < n; ++i) { int v = part[i]; part[i] = run; run += v; }
    }
}

__global__ __launch_bounds__(256) void scan_final(
    const int* __restrict__ deg, const int* __restrict__ part,
    int* __restrict__ rowptr, int n)
{
    __shared__ int lds[256];
    int b = blockIdx.x, t = threadIdx.x;
    int base = b * 1024 + t * 4;
    int v[4]; int tsum = 0;
    #pragma unroll
    for (int k = 0; k < 4; ++k) {
        v[k] = (base + k < n) ? deg[base + k] : 0;
        tsum += v[k];
    }
    lds[t] = tsum; __syncthreads();
    for (int off = 1; off < 256; off <<= 1) {
        int x = (t >= off) ? lds[t - off] : 0;
        __syncthreads();
        lds[t] += x;
        __syncthreads();
    }
    int run = lds[t] - tsum + part[b];  // exclusive prefix of this thread
    #pragma unroll
    for (int k = 0; k < 4; ++k) {
        if (base + k < n) rowptr[base + k] = run;
        run += v[k];
    }
}

// ---- counting-sort edges by dst ---------------------------------------------
__global__ __launch_bounds__(256) void csr_build(
    const int* __restrict__ src, const int* __restrict__ dst,
    int* __restrict__ cursor, int* __restrict__ csr_src, int nedges)
{
    int i = blockIdx.x * 256 + threadIdx.x;
    int stride = gridDim.x * 256;
    for (int e = i; e < nedges; e += stride) {
        int pos = atomicAdd(cursor + dst[e], 1);
        csr_src[pos] = src[e];
    }
}

// ---- W -> bf16 W^T (Wt[n*128+k] = W[k*128+n]) -------------------------------
__global__ __launch_bounds__(256) void wt_kernel(
    const float* __restrict__ W0, const float* __restrict__ W1,
    const float* __restrict__ W2, unsigned short* __restrict__ Wt)
{
    int i = blockIdx.x * 256 + threadIdx.x;
    if (i >= 3 * DD * DD) return;
    int w = i >> 14, r = i & (DD * DD - 1);
    int c = r >> 7, k = r & (DD - 1);
    const float* W = (w == 0) ? W0 : ((w == 1) ? W1 : W2);
    Wt[i] = f2bf(W[k * DD + c]);
}

// ---- MFMA GEMM, fp32 X input converted in-kernel ----------------------------
// M[r][c] = bf16( (X @ W)[r][c] * rs_out[r] );  wave=16 rows, block=64 rows.
__global__ __launch_bounds__(256) void mfma_gemm(
    const float* __restrict__ X,            // [nrows,128] fp32
    const unsigned short* __restrict__ Wt,  // [128 n][128 k] bf16 (W^T)
    const float* __restrict__ rs,           // deg_out^-1/2 per row
    unsigned short* __restrict__ M,         // [nrows,128] bf16
    int nrows)
{
    int wid  = threadIdx.x >> 6;
    int lane = threadIdx.x & 63;
    int quad = lane >> 4;
    int l16  = lane & 15;
    int base = blockIdx.x * 64 + wid * 16;
    if (base >= nrows) return;

    int arow = base + l16;
    if (arow >= nrows) arow = nrows - 1;    // clamped rows only feed discarded outputs
    bf16x8 a[4];
    #pragma unroll
    for (int kk = 0; kk < 4; ++kk) {
        const float4* p = (const float4*)(X + (size_t)arow * DD + kk * 32 + quad * 8);
        float4 u = p[0], w = p[1];
        bf16x8 t;
        t[0] = (short)f2bf(u.x); t[1] = (short)f2bf(u.y);
        t[2] = (short)f2bf(u.z); t[3] = (short)f2bf(u.w);
        t[4] = (short)f2bf(w.x); t[5] = (short)f2bf(w.y);
        t[6] = (short)f2bf(w.z); t[7] = (short)f2bf(w.w);
        a[kk] = t;
    }

    float rsv[4]; int orow0 = base + quad * 4;
    #pragma unroll
    for (int r = 0; r < 4; ++r) {
        int orow = orow0 + r;
        rsv[r] = rs[orow < nrows ? orow : 0];
    }

    #pragma unroll
    for (int ct = 0; ct < 8; ++ct) {
        f32x4 acc = {0.f, 0.f, 0.f, 0.f};
        const unsigned short* wp = Wt + (size_t)(ct * 16 + l16) * DD + quad * 8;
        #pragma unroll
        for (int kk = 0; kk < 4; ++kk) {
            bf16x8 b = *(const bf16x8*)(wp + kk * 32);
            acc = __builtin_amdgcn_mfma_f32_16x16x32_bf16(a[kk], b, acc, 0, 0, 0);
        }
        #pragma unroll
        for (int r = 0; r < 4; ++r) {
            int orow = orow0 + r;
            if (orow < nrows)
                M[(size_t)orow * DD + ct * 16 + l16] = f2bf(acc[r] * rsv[r]);
        }
    }
}

// ---- gather aggregation: one wave per dst row, atomic-free ------------------
__global__ __launch_bounds__(256) void gather_A(
    const unsigned short* __restrict__ mA0, const unsigned short* __restrict__ mB2,
    const int* __restrict__ csr0, const int* __restrict__ rp0, const int* __restrict__ dg0,
    const int* __restrict__ csr2, const int* __restrict__ rp2, const int* __restrict__ dg2,
    const float* __restrict__ rdin0, const float* __restrict__ rdin2,
    const float* __restrict__ b0, const float* __restrict__ b2,
    float* __restrict__ out)
{
    int wid = threadIdx.x >> 6, lane = threadIdx.x & 63;
    int d = blockIdx.x * 4 + wid;
    if (d >= NA) return;

    float a0 = 0.f, a1 = 0.f;
    {
        int st = rp0[d], n = dg0[d], i = 0;
        for (; i + 1 < n; i += 2) {
            int sA = csr0[st + i], sB = csr0[st + i + 1];
            unsigned int uA = *(const unsigned int*)(mA0 + (size_t)sA * DD + lane * 2);
            unsigned int uB = *(const unsigned int*)(mA0 + (size_t)sB * DD + lane * 2);
            a0 += bf2f(uA & 0xffff) + bf2f(uB & 0xffff);
            a1 += bf2f(uA >> 16)    + bf2f(uB >> 16);
        }
        if (i < n) {
            int s = csr0[st + i];
            unsigned int u = *(const unsigned int*)(mA0 + (size_t)s * DD + lane * 2);
            a0 += bf2f(u & 0xffff); a1 += bf2f(u >> 16);
        }
    }
    float c0 = 0.f, c1 = 0.f;
    {
        int st = rp2[d], n = dg2[d], i = 0;
        for (; i + 1 < n; i += 2) {
            int sA = csr2[st + i], sB = csr2[st + i + 1];
            unsigned int uA = *(const unsigned int*)(mB2 + (size_t)sA * DD + lane * 2);
            unsigned int uB = *(const unsigned int*)(mB2 + (size_t)sB * DD + lane * 2);
            c0 += bf2f(uA & 0xffff) + bf2f(uB & 0xffff);
            c1 += bf2f(uA >> 16)    + bf2f(uB >> 16);
        }
        if (i < n) {
            int s = csr2[st + i];
            unsigned int u = *(const unsigned int*)(mB2 + (size_t)s * DD + lane * 2);
            c0 += bf2f(u & 0xffff); c1 += bf2f(u >> 16);
        }
    }
    float r0 = rdin0[d], r2 = rdin2[d];
    int col = lane * 2;
    float2 o;
    o.x = a0 * r0 + c0 * r2 + b0[col]     + b2[col];
    o.y = a1 * r0 + c1 * r2 + b0[col + 1] + b2[col + 1];
    *(float2*)(out + (size_t)d * DD + col) = o;
}

__global__ __launch_bounds__(256) void gather_B(
    const unsigned short* __restrict__ mA1,
    const int* __restrict__ csr1, const int* __restrict__ rp1, const int* __restrict__ dg1,
    const float* __restrict__ rdin1, const float* __restrict__ b1,
    float* __restrict__ out)
{
    int wid = threadIdx.x >> 6, lane = threadIdx.x & 63;
    int d = blockIdx.x * 4 + wid;
    if (d >= NB) return;

    float a0 = 0.f, a1 = 0.f;
    int st = rp1[d], n = dg1[d], i = 0;
    for (; i + 1 < n; i += 2) {
        int sA = csr1[st + i], sB = csr1[st + i + 1];
        unsigned int uA = *(const unsigned int*)(mA1 + (size_t)sA * DD + lane * 2);
        unsigned int uB = *(const unsigned int*)(mA1 + (size_t)sB * DD + lane * 2);
        a0 += bf2f(uA & 0xffff) + bf2f(uB & 0xffff);
        a1 += bf2f(uA >> 16)    + bf2f(uB >> 16);
    }
    if (i < n) {
        int s = csr1[st + i];
        unsigned int u = *(const unsigned int*)(mA1 + (size_t)s * DD + lane * 2);
        a0 += bf2f(u & 0xffff); a1 += bf2f(u >> 16);
    }
    float r1 = rdin1[d];
    int col = lane * 2;
    float2 o;
    o.x = a0 * r1 + b1[col];
    o.y = a1 * r1 + b1[col + 1];
    *(float2*)(out + (size_t)d * DD + col) = o;
}

extern "C" void kernel_launch(void* const* d_in, const int* in_sizes, int n_in,
                              void* d_out, int out_size, void* d_ws, size_t ws_size,
                              hipStream_t stream) {
    const float* hA = (const float*)d_in[0];
    const float* hB = (const float*)d_in[1];
    const float* W0 = (const float*)d_in[2];
    const float* b0 = (const float*)d_in[3];
    const float* W1 = (const float*)d_in[4];
    const float* b1 = (const float*)d_in[5];
    const float* W2 = (const float*)d_in[6];
    const float* b2 = (const float*)d_in[7];
    const int* s0 = (const int*)d_in[8];
    const int* d0 = (const int*)d_in[9];
    const int* s1 = (const int*)d_in[10];
    const int* d1 = (const int*)d_in[11];
    const int* s2 = (const int*)d_in[12];
    const int* d2 = (const int*)d_in[13];
    float* out = (float*)d_out;
    char* ws = (char*)d_ws;

    // ws layout (all offsets 16B-aligned)
    unsigned short* mA0 = (unsigned short*)(ws + 0);          // 12.8 MB
    unsigned short* mA1 = (unsigned short*)(ws + 12800000);   // 12.8 MB
    unsigned short* mB2 = (unsigned short*)(ws + 25600000);   // 5.12 MB
    unsigned short* Wt  = (unsigned short*)(ws + 30720000);   // 96 KB
    float* rdeg         = (float*)(ws + 30818304);            // 960 KB
    int*   ideg         = (int*)  (ws + 31778304);            // 960 KB
    int*   rp           = (int*)  (ws + 32738304);            // rp0[NA] rp1[NB] rp2[NA]
    int*   cur          = (int*)  (ws + 33218304);            // same layout
    int*   part         = (int*)  (ws + 33698304);            // 3 x 64 ints
    int*   csr0         = (int*)  (ws + 33699328);            // 2.4 MB
    int*   csr1         = (int*)  (ws + 36099328);            // 1.2 MB
    int*   csr2         = (int*)  (ws + 37299328);            // 1.2 MB

    const int* din0 = ideg + NA;
    const int* din1 = ideg + 3 * NA;
    const int* din2 = ideg + 3 * NA + 2 * NB;
    const float* rdin0 = rdeg + NA;
    const float* rdin1 = rdeg + 3 * NA;
    const float* rdin2 = rdeg + 3 * NA + 2 * NB;

    hipMemsetAsync(ideg, 0, DEG_TOT * sizeof(int), stream);
    deg_kernel<<<2048, 256, 0, stream>>>(s0, d0, s1, d1, s2, d2, ideg);
    rsqrt_kernel<<<(DEG_TOT + 255) / 256, 256, 0, stream>>>(ideg, rdeg);

    // exclusive scans of the three in-degree arrays -> rowptrs
    scan_reduce<<<49, 256, 0, stream>>>(din0, part,       NA);
    scan_reduce<<<20, 256, 0, stream>>>(din1, part + 64,  NB);
    scan_reduce<<<49, 256, 0, stream>>>(din2, part + 128, NA);
    scan_spine<<<1, 64, 0, stream>>>(part,       49);
    scan_spine<<<1, 64, 0, stream>>>(part + 64,  20);
    scan_spine<<<1, 64, 0, stream>>>(part + 128, 49);
    scan_final<<<49, 256, 0, stream>>>(din0, part,       rp,           NA);
    scan_final<<<20, 256, 0, stream>>>(din1, part + 64,  rp + NA,      NB);
    scan_final<<<49, 256, 0, stream>>>(din2, part + 128, rp + NA + NB, NA);

    hipMemcpyAsync(cur, rp, (2 * NA + NB) * sizeof(int), hipMemcpyDeviceToDevice, stream);
    csr_build<<<1024, 256, 0, stream>>>(s0, d0, cur,           csr0, NE0);
    csr_build<<<1024, 256, 0, stream>>>(s1, d1, cur + NA,      csr1, NE1);
    csr_build<<<1024, 256, 0, stream>>>(s2, d2, cur + NA + NB, csr2, NE2);

    wt_kernel<<<(3 * DD * DD + 255) / 256, 256, 0, stream>>>(W0, W1, W2, Wt);

    // m = bf16( (X @ W) * deg_out^{-1/2} )
    mfma_gemm<<<(NA + 63) / 64, 256, 0, stream>>>(hA, Wt,         rdeg,               mA0, NA);
    mfma_gemm<<<(NA + 63) / 64, 256, 0, stream>>>(hA, Wt + 16384, rdeg + 2 * NA,      mA1, NA);
    mfma_gemm<<<(NB + 63) / 64, 256, 0, stream>>>(hB, Wt + 32768, rdeg + 3 * NA + NB, mB2, NB);

    // atomic-free aggregation, one wave per dst row
    gather_A<<<(NA + 3) / 4, 256, 0, stream>>>(mA0, mB2,
        csr0, rp, din0, csr2, rp + NA + NB, din2, rdin0, rdin2, b0, b2, out);
    gather_B<<<(NB + 3) / 4, 256, 0, stream>>>(mA1,
        csr1, rp + NA, din1, rdin1, b1, out + (size_t)NA * DD);
}

// Round 3
// 400.378 us; speedup vs baseline: 5.7748x; 1.1234x over previous
//
#include <hip/hip_runtime.h>

#define NA 50000
#define NB 20000
#define NE0 600000
#define NE1 300000
#define NE2 300000
#define DD 128
#define DEG_TOT (4 * NA + 2 * NB)
#define SUB 16384   // LDS histogram subrange (64 KB)

// hist partial layout (ints, within P):
// P0 dout0: G=16,K=NA @0 ; P1 din0: G=16,K=NA @800000 ; P2 dout1: G=8,K=NA @1600000
// P3 din1: G=8,K=NB @2000000 ; P4 dout2: G=8,K=NB @2160000 ; P5 din2: G=8,K=NA @2320000
#define P_TOT 2720000

typedef short bf16x8 __attribute__((ext_vector_type(8)));
typedef float f32x4 __attribute__((ext_vector_type(4)));

__device__ __forceinline__ unsigned short f2bf(float f) {
    union { float f; unsigned int u; } v; v.f = f;
    unsigned int r = v.u + 0x7fffu + ((v.u >> 16) & 1u);   // RNE
    return (unsigned short)(r >> 16);
}
__device__ __forceinline__ float bf2f(unsigned int u16) {
    union { float f; unsigned int u; } v; v.u = u16 << 16;
    return v.f;
}

// ---- LDS-privatized histograms: no global atomics ---------------------------
__global__ __launch_bounds__(256) void hist_kernel(
    const int* __restrict__ k0, const int* __restrict__ k1, const int* __restrict__ k2,
    const int* __restrict__ k3, const int* __restrict__ k4, const int* __restrict__ k5,
    int* __restrict__ P)
{
    __shared__ int h[SUB];
    const int cfg = blockIdx.z;
    const int En[6] = {NE0, NE0, NE1, NE1, NE2, NE2};
    const int Kn[6] = {NA, NA, NA, NB, NB, NA};
    const int Gn[6] = {16, 16, 8, 8, 8, 8};
    const int Po[6] = {0, 800000, 1600000, 2000000, 2160000, 2320000};
    int E = En[cfg], K = Kn[cfg], G = Gn[cfg];
    int sub = blockIdx.x, g = blockIdx.y;
    int nsub = (K + SUB - 1) / SUB;
    if (sub >= nsub || g >= G) return;
    const int* keys = cfg == 0 ? k0 : cfg == 1 ? k1 : cfg == 2 ? k2
                    : cfg == 3 ? k3 : cfg == 4 ? k4 : k5;
    int lo = sub * SUB;
    int hi = min(K, lo + SUB);
    int cnt = hi - lo;
    for (int i = threadIdx.x; i < cnt; i += 256) h[i] = 0;
    __syncthreads();
    int per = (E + G - 1) / G;
    int e1 = min(E, g * per + per);
    for (int e = g * per + threadIdx.x; e < e1; e += 256) {
        int k = keys[e];
        if (k >= lo && k < hi) atomicAdd(&h[k - lo], 1);
    }
    __syncthreads();
    int* outp = P + Po[cfg] + g * K + lo;
    for (int i = threadIdx.x; i < cnt; i += 256) outp[i] = h[i];
}

// ---- sum partials -> integer degree + rsqrt ---------------------------------
__global__ __launch_bounds__(256) void reduce_kernel(
    const int* __restrict__ P, int* __restrict__ ideg, float* __restrict__ rdeg)
{
    int i = blockIdx.x * 256 + threadIdx.x;
    if (i >= DEG_TOT) return;
    int h, k;
    if      (i < NA)            { h = 0; k = i; }
    else if (i < 2 * NA)        { h = 1; k = i - NA; }
    else if (i < 3 * NA)        { h = 2; k = i - 2 * NA; }
    else if (i < 3 * NA + NB)   { h = 3; k = i - 3 * NA; }
    else if (i < 3 * NA + 2*NB) { h = 4; k = i - 3 * NA - NB; }
    else                        { h = 5; k = i - 3 * NA - 2 * NB; }
    const int Po[6] = {0, 800000, 1600000, 2000000, 2160000, 2320000};
    const int Gn[6] = {16, 16, 8, 8, 8, 8};
    const int Kn[6] = {NA, NA, NA, NB, NB, NA};
    const int* p = P + Po[h] + k;
    int K = Kn[h], G = Gn[h], s = 0;
    for (int g = 0; g < G; ++g) s += p[g * K];
    ideg[i] = s;
    rdeg[i] = rsqrtf(fmaxf((float)s, 1.f));
}

// ---- 3-kernel exclusive scan, fused across the 3 din arrays -----------------
__global__ __launch_bounds__(256) void scan_reduce(
    const int* __restrict__ ideg, int* __restrict__ spart)
{
    __shared__ int lds[256];
    int y = blockIdx.y;
    const int off[3] = {NA, 3 * NA, 3 * NA + 2 * NB};
    const int nn[3]  = {NA, NB, NA};
    int n = nn[y];
    int b = blockIdx.x, t = threadIdx.x;
    if (b * 1024 >= n) return;
    const int* deg = ideg + off[y];
    int base = b * 1024 + t * 4;
    int s = 0;
    #pragma unroll
    for (int k = 0; k < 4; ++k) { int i = base + k; if (i < n) s += deg[i]; }
    lds[t] = s; __syncthreads();
    for (int o = 128; o > 0; o >>= 1) {
        if (t < o) lds[t] += lds[t + o];
        __syncthreads();
    }
    if (t == 0) spart[y * 64 + b] = lds[0];
}

__global__ void spine_kernel(int* __restrict__ spart) {   // block = 192
    int w = threadIdx.x >> 6, lane = threadIdx.x & 63;
    const int nblk[3] = {49, 20, 49};
    int n = nblk[w];
    int* p = spart + w * 64;
    int orig = (lane < n) ? p[lane] : 0;
    int v = orig;
    #pragma unroll
    for (int o = 1; o < 64; o <<= 1) {
        int u = __shfl_up(v, o);
        if (lane >= o) v += u;
    }
    if (lane < n) p[lane] = v - orig;
}

__global__ __launch_bounds__(256) void scan_final(
    const int* __restrict__ ideg, const int* __restrict__ spart,
    int* __restrict__ rp)
{
    __shared__ int lds[256];
    int y = blockIdx.y;
    const int off[3] = {NA, 3 * NA, 3 * NA + 2 * NB};
    const int nn[3]  = {NA, NB, NA};
    const int ro[3]  = {0, NA, NA + NB};
    int n = nn[y];
    int b = blockIdx.x, t = threadIdx.x;
    if (b * 1024 >= n) return;
    const int* deg = ideg + off[y];
    int* rowptr = rp + ro[y];
    int base = b * 1024 + t * 4;
    int v[4]; int tsum = 0;
    #pragma unroll
    for (int k = 0; k < 4; ++k) {
        v[k] = (base + k < n) ? deg[base + k] : 0;
        tsum += v[k];
    }
    lds[t] = tsum; __syncthreads();
    for (int o = 1; o < 256; o <<= 1) {
        int x = (t >= o) ? lds[t - o] : 0;
        __syncthreads();
        lds[t] += x;
        __syncthreads();
    }
    int run = lds[t] - tsum + spart[y * 64 + b];
    #pragma unroll
    for (int k = 0; k < 4; ++k) {
        if (base + k < n) rowptr[base + k] = run;
        run += v[k];
    }
}

// ---- din partials -> per-(slice,key) exclusive offsets, in place ------------
__global__ __launch_bounds__(256) void offsets_kernel(
    int* __restrict__ P, const int* __restrict__ rp)
{
    int i = blockIdx.x * 256 + threadIdx.x;
    if (i >= 2 * NA + NB) return;
    int base, G, K, d, run;
    if (i < NA)           { base = 800000;  G = 16; K = NA; d = i;           run = rp[d]; }
    else if (i < NA + NB) { base = 2000000; G = 8;  K = NB; d = i - NA;      run = rp[NA + d]; }
    else                  { base = 2320000; G = 8;  K = NA; d = i - NA - NB; run = rp[NA + NB + d]; }
    int* p = P + base + d;
    for (int g = 0; g < G; ++g) {
        int t = p[g * K];
        p[g * K] = run;
        run += t;
    }
}

// ---- counting-sort placement with LDS cursors: no global atomics ------------
__global__ __launch_bounds__(256) void place_kernel(
    const int* __restrict__ s0, const int* __restrict__ d0,
    const int* __restrict__ s1, const int* __restrict__ d1,
    const int* __restrict__ s2, const int* __restrict__ d2,
    int* __restrict__ P, int* __restrict__ csr0, int* __restrict__ csr1,
    int* __restrict__ csr2)
{
    __shared__ int cur[SUB];
    const int cfg = blockIdx.z;
    const int En[3] = {NE0, NE1, NE2};
    const int Kn[3] = {NA, NB, NA};
    const int Gn[3] = {16, 8, 8};
    const int Po[3] = {800000, 2000000, 2320000};
    int E = En[cfg], K = Kn[cfg], G = Gn[cfg];
    int sub = blockIdx.x, g = blockIdx.y;
    int nsub = (K + SUB - 1) / SUB;
    if (sub >= nsub || g >= G) return;
    const int* src = cfg == 0 ? s0 : cfg == 1 ? s1 : s2;
    const int* dst = cfg == 0 ? d0 : cfg == 1 ? d1 : d2;
    int* csr = cfg == 0 ? csr0 : cfg == 1 ? csr1 : csr2;
    int lo = sub * SUB, hi = min(K, lo + SUB), cnt = hi - lo;
    const int* off = P + Po[cfg] + g * K + lo;
    for (int i = threadIdx.x; i < cnt; i += 256) cur[i] = off[i];
    __syncthreads();
    int per = (E + G - 1) / G;
    int e1 = min(E, g * per + per);
    for (int e = g * per + threadIdx.x; e < e1; e += 256) {
        int d = dst[e];
        if (d >= lo && d < hi) {
            int pos = atomicAdd(&cur[d - lo], 1);   // LDS atomic only
            csr[pos] = src[e];
        }
    }
}

// ---- W -> bf16 W^T ----------------------------------------------------------
__global__ __launch_bounds__(256) void wt_kernel(
    const float* __restrict__ W0, const float* __restrict__ W1,
    const float* __restrict__ W2, unsigned short* __restrict__ Wt)
{
    int i = blockIdx.x * 256 + threadIdx.x;
    if (i >= 3 * DD * DD) return;
    int w = i >> 14, r = i & (DD * DD - 1);
    int c = r >> 7, k = r & (DD - 1);
    const float* W = (w == 0) ? W0 : ((w == 1) ? W1 : W2);
    Wt[i] = f2bf(W[k * DD + c]);
}

// ---- fused MFMA GEMM (3 relations via blockIdx.z) ---------------------------
__global__ __launch_bounds__(256) void mfma_gemm(
    const float* __restrict__ hA, const float* __restrict__ hB,
    const unsigned short* __restrict__ Wt, const float* __restrict__ rdeg,
    unsigned short* __restrict__ mA0, unsigned short* __restrict__ mA1,
    unsigned short* __restrict__ mB2)
{
    int z = blockIdx.z;
    const float* X = (z == 2) ? hB : hA;
    const unsigned short* W = Wt + z * 16384;
    const float* rs = rdeg + (z == 0 ? 0 : z == 1 ? 2 * NA : 3 * NA + NB);
    unsigned short* M = z == 0 ? mA0 : z == 1 ? mA1 : mB2;
    int nrows = (z == 2) ? NB : NA;

    int wid  = threadIdx.x >> 6;
    int lane = threadIdx.x & 63;
    int quad = lane >> 4;
    int l16  = lane & 15;
    int base = blockIdx.x * 64 + wid * 16;
    if (base >= nrows) return;

    int arow = base + l16;
    if (arow >= nrows) arow = nrows - 1;
    bf16x8 a[4];
    #pragma unroll
    for (int kk = 0; kk < 4; ++kk) {
        const float4* p = (const float4*)(X + (size_t)arow * DD + kk * 32 + quad * 8);
        float4 u = p[0], w = p[1];
        bf16x8 t;
        t[0] = (short)f2bf(u.x); t[1] = (short)f2bf(u.y);
        t[2] = (short)f2bf(u.z); t[3] = (short)f2bf(u.w);
        t[4] = (short)f2bf(w.x); t[5] = (short)f2bf(w.y);
        t[6] = (short)f2bf(w.z); t[7] = (short)f2bf(w.w);
        a[kk] = t;
    }

    float rsv[4]; int orow0 = base + quad * 4;
    #pragma unroll
    for (int r = 0; r < 4; ++r) {
        int orow = orow0 + r;
        rsv[r] = rs[orow < nrows ? orow : 0];
    }

    #pragma unroll
    for (int ct = 0; ct < 8; ++ct) {
        f32x4 acc = {0.f, 0.f, 0.f, 0.f};
        const unsigned short* wp = W + (size_t)(ct * 16 + l16) * DD + quad * 8;
        #pragma unroll
        for (int kk = 0; kk < 4; ++kk) {
            bf16x8 b = *(const bf16x8*)(wp + kk * 32);
            acc = __builtin_amdgcn_mfma_f32_16x16x32_bf16(a[kk], b, acc, 0, 0, 0);
        }
        #pragma unroll
        for (int r = 0; r < 4; ++r) {
            int orow = orow0 + r;
            if (orow < nrows)
                M[(size_t)orow * DD + ct * 16 + l16] = f2bf(acc[r] * rsv[r]);
        }
    }
}

// ---- gather aggregation: one wave per dst row -------------------------------
__global__ __launch_bounds__(256) void gather_A(
    const unsigned short* __restrict__ mA0, const unsigned short* __restrict__ mB2,
    const int* __restrict__ csr0, const int* __restrict__ rp0, const int* __restrict__ dg0,
    const int* __restrict__ csr2, const int* __restrict__ rp2, const int* __restrict__ dg2,
    const float* __restrict__ rdin0, const float* __restrict__ rdin2,
    const float* __restrict__ b0, const float* __restrict__ b2,
    float* __restrict__ out)
{
    int wid = threadIdx.x >> 6, lane = threadIdx.x & 63;
    int d = blockIdx.x * 4 + wid;
    if (d >= NA) return;

    float a0 = 0.f, a1 = 0.f;
    {
        int st = rp0[d], n = dg0[d], i = 0;
        for (; i + 1 < n; i += 2) {
            int sA = csr0[st + i], sB = csr0[st + i + 1];
            unsigned int uA = *(const unsigned int*)(mA0 + (size_t)sA * DD + lane * 2);
            unsigned int uB = *(const unsigned int*)(mA0 + (size_t)sB * DD + lane * 2);
            a0 += bf2f(uA & 0xffff) + bf2f(uB & 0xffff);
            a1 += bf2f(uA >> 16)    + bf2f(uB >> 16);
        }
        if (i < n) {
            int s = csr0[st + i];
            unsigned int u = *(const unsigned int*)(mA0 + (size_t)s * DD + lane * 2);
            a0 += bf2f(u & 0xffff); a1 += bf2f(u >> 16);
        }
    }
    float c0 = 0.f, c1 = 0.f;
    {
        int st = rp2[d], n = dg2[d], i = 0;
        for (; i + 1 < n; i += 2) {
            int sA = csr2[st + i], sB = csr2[st + i + 1];
            unsigned int uA = *(const unsigned int*)(mB2 + (size_t)sA * DD + lane * 2);
            unsigned int uB = *(const unsigned int*)(mB2 + (size_t)sB * DD + lane * 2);
            c0 += bf2f(uA & 0xffff) + bf2f(uB & 0xffff);
            c1 += bf2f(uA >> 16)    + bf2f(uB >> 16);
        }
        if (i < n) {
            int s = csr2[st + i];
            unsigned int u = *(const unsigned int*)(mB2 + (size_t)s * DD + lane * 2);
            c0 += bf2f(u & 0xffff); c1 += bf2f(u >> 16);
        }
    }
    float r0 = rdin0[d], r2 = rdin2[d];
    int col = lane * 2;
    float2 o;
    o.x = a0 * r0 + c0 * r2 + b0[col]     + b2[col];
    o.y = a1 * r0 + c1 * r2 + b0[col + 1] + b2[col + 1];
    *(float2*)(out + (size_t)d * DD + col) = o;
}

__global__ __launch_bounds__(256) void gather_B(
    const unsigned short* __restrict__ mA1,
    const int* __restrict__ csr1, const int* __restrict__ rp1, const int* __restrict__ dg1,
    const float* __restrict__ rdin1, const float* __restrict__ b1,
    float* __restrict__ out)
{
    int wid = threadIdx.x >> 6, lane = threadIdx.x & 63;
    int d = blockIdx.x * 4 + wid;
    if (d >= NB) return;

    float a0 = 0.f, a1 = 0.f;
    int st = rp1[d], n = dg1[d], i = 0;
    for (; i + 1 < n; i += 2) {
        int sA = csr1[st + i], sB = csr1[st + i + 1];
        unsigned int uA = *(const unsigned int*)(mA1 + (size_t)sA * DD + lane * 2);
        unsigned int uB = *(const unsigned int*)(mA1 + (size_t)sB * DD + lane * 2);
        a0 += bf2f(uA & 0xffff) + bf2f(uB & 0xffff);
        a1 += bf2f(uA >> 16)    + bf2f(uB >> 16);
    }
    if (i < n) {
        int s = csr1[st + i];
        unsigned int u = *(const unsigned int*)(mA1 + (size_t)s * DD + lane * 2);
        a0 += bf2f(u & 0xffff); a1 += bf2f(u >> 16);
    }
    float r1 = rdin1[d];
    int col = lane * 2;
    float2 o;
    o.x = a0 * r1 + b1[col];
    o.y = a1 * r1 + b1[col + 1];
    *(float2*)(out + (size_t)d * DD + col) = o;
}

extern "C" void kernel_launch(void* const* d_in, const int* in_sizes, int n_in,
                              void* d_out, int out_size, void* d_ws, size_t ws_size,
                              hipStream_t stream) {
    const float* hA = (const float*)d_in[0];
    const float* hB = (const float*)d_in[1];
    const float* W0 = (const float*)d_in[2];
    const float* b0 = (const float*)d_in[3];
    const float* W1 = (const float*)d_in[4];
    const float* b1 = (const float*)d_in[5];
    const float* W2 = (const float*)d_in[6];
    const float* b2 = (const float*)d_in[7];
    const int* s0 = (const int*)d_in[8];
    const int* d0 = (const int*)d_in[9];
    const int* s1 = (const int*)d_in[10];
    const int* d1 = (const int*)d_in[11];
    const int* s2 = (const int*)d_in[12];
    const int* d2 = (const int*)d_in[13];
    float* out = (float*)d_out;
    char* ws = (char*)d_ws;

    // ws layout (bytes, 64B-aligned)
    unsigned short* mA0 = (unsigned short*)(ws + 0);          // 12.8 MB
    unsigned short* mA1 = (unsigned short*)(ws + 12800000);   // 12.8 MB
    unsigned short* mB2 = (unsigned short*)(ws + 25600000);   // 5.12 MB
    unsigned short* Wt  = (unsigned short*)(ws + 30720000);   // 96 KB
    float* rdeg         = (float*)(ws + 30818304);            // 960 KB
    int*   ideg         = (int*)  (ws + 31778304);            // 960 KB
    int*   rp           = (int*)  (ws + 32738304);            // rp0[NA] rp1[NB] rp2[NA]
    int*   spart        = (int*)  (ws + 33218304);            // 3*64 ints
    int*   P            = (int*)  (ws + 33219328);            // 10.88 MB partials
    int*   csr0         = (int*)  (ws + 44099328);            // 2.4 MB
    int*   csr1         = (int*)  (ws + 46499328);            // 1.2 MB
    int*   csr2         = (int*)  (ws + 47699328);            // 1.2 MB

    const int* din0 = ideg + NA;
    const int* din1 = ideg + 3 * NA;
    const int* din2 = ideg + 3 * NA + 2 * NB;
    const float* rdin0 = rdeg + NA;
    const float* rdin1 = rdeg + 3 * NA;
    const float* rdin2 = rdeg + 3 * NA + 2 * NB;

    hist_kernel<<<dim3(4, 16, 6), 256, 0, stream>>>(s0, d0, s1, d1, s2, d2, P);
    reduce_kernel<<<(DEG_TOT + 255) / 256, 256, 0, stream>>>(P, ideg, rdeg);

    scan_reduce<<<dim3(49, 3), 256, 0, stream>>>(ideg, spart);
    spine_kernel<<<1, 192, 0, stream>>>(spart);
    scan_final<<<dim3(49, 3), 256, 0, stream>>>(ideg, spart, rp);

    offsets_kernel<<<(2 * NA + NB + 255) / 256, 256, 0, stream>>>(P, rp);
    place_kernel<<<dim3(4, 16, 3), 256, 0, stream>>>(s0, d0, s1, d1, s2, d2,
                                                     P, csr0, csr1, csr2);

    wt_kernel<<<(3 * DD * DD + 255) / 256, 256, 0, stream>>>(W0, W1, W2, Wt);
    mfma_gemm<<<dim3((NA + 63) / 64, 1, 3), 256, 0, stream>>>(hA, hB, Wt, rdeg,
                                                              mA0, mA1, mB2);

    gather_A<<<(NA + 3) / 4, 256, 0, stream>>>(mA0, mB2,
        csr0, rp, din0, csr2, rp + NA + NB, din2, rdin0, rdin2, b0, b2, out);
    gather_B<<<(NB + 3) / 4, 256, 0, stream>>>(mA1,
        csr1, rp + NA, din1, rdin1, b1, out + (size_t)NA * DD);
}

// Round 4
// 307.276 us; speedup vs baseline: 7.5245x; 1.3030x over previous
//
#include <hip/hip_runtime.h>

#define NA 50000
#define NB 20000
#define NE0 600000
#define NE1 300000
#define NE2 300000
#define DD 128
#define DEG_TOT (4 * NA + 2 * NB)
#define SUB 16384     // LDS histogram subrange (64 KB)
#define PER 18750     // edges per group: NE0/32 = NE1/16 = NE2/16

// P partial layout (ints):
// cfg0 dout0 G=32,K=NA @0        ; cfg1 din0 G=32,K=NA @1600000
// cfg2 dout1 G=16,K=NA @3200000  ; cfg3 din1 G=16,K=NB @4000000
// cfg4 dout2 G=16,K=NB @4320000  ; cfg5 din2 G=16,K=NA @4640000
#define P_TOT 5440000

typedef short bf16x8 __attribute__((ext_vector_type(8)));
typedef float f32x4 __attribute__((ext_vector_type(4)));

__device__ __forceinline__ unsigned short f2bf(float f) {
    union { float f; unsigned int u; } v; v.f = f;
    unsigned int r = v.u + 0x7fffu + ((v.u >> 16) & 1u);   // RNE
    return (unsigned short)(r >> 16);
}
__device__ __forceinline__ float bf2f(unsigned int u16) {
    union { float f; unsigned int u; } v; v.u = u16 << 16;
    return v.f;
}

// ---- LDS-privatized histograms; din cfgs also record each edge's rank -------
__global__ __launch_bounds__(512) void hist_kernel(
    const int* __restrict__ s0, const int* __restrict__ d0,
    const int* __restrict__ s1, const int* __restrict__ d1,
    const int* __restrict__ s2, const int* __restrict__ d2,
    int* __restrict__ P,
    int* __restrict__ rank0, int* __restrict__ rank1, int* __restrict__ rank2)
{
    __shared__ int h[SUB];
    const int cfg = blockIdx.z;
    const int En[6] = {NE0, NE0, NE1, NE1, NE2, NE2};
    const int Kn[6] = {NA, NA, NA, NB, NB, NA};
    const int Gn[6] = {32, 32, 16, 16, 16, 16};
    const int Po[6] = {0, 1600000, 3200000, 4000000, 4320000, 4640000};
    int E = En[cfg], K = Kn[cfg], G = Gn[cfg];
    int sub = blockIdx.x, g = blockIdx.y;
    int nsub = (K + SUB - 1) / SUB;
    if (sub >= nsub || g >= G) return;
    const int* keys = cfg == 0 ? s0 : cfg == 1 ? d0 : cfg == 2 ? s1
                    : cfg == 3 ? d1 : cfg == 4 ? s2 : d2;
    int* rk = cfg == 1 ? rank0 : cfg == 3 ? rank1 : cfg == 5 ? rank2 : (int*)0;
    int lo = sub * SUB;
    int hi = min(K, lo + SUB);
    int cnt = hi - lo;
    for (int i = threadIdx.x; i < cnt; i += 512) h[i] = 0;
    __syncthreads();
    int e1 = min(E, g * PER + PER);
    for (int e = g * PER + threadIdx.x; e < e1; e += 512) {
        int k = keys[e];
        if (k >= lo && k < hi) {
            int r = atomicAdd(&h[k - lo], 1);
            if (rk) rk[e] = r;
        }
    }
    __syncthreads();
    int* outp = P + Po[cfg] + g * K + lo;
    for (int i = threadIdx.x; i < cnt; i += 512) outp[i] = h[i];
}

// ---- sum partials -> integer degree + rsqrt ---------------------------------
__global__ __launch_bounds__(256) void reduce_kernel(
    const int* __restrict__ P, int* __restrict__ ideg, float* __restrict__ rdeg)
{
    int i = blockIdx.x * 256 + threadIdx.x;
    if (i >= DEG_TOT) return;
    int h, k;
    if      (i < NA)            { h = 0; k = i; }
    else if (i < 2 * NA)        { h = 1; k = i - NA; }
    else if (i < 3 * NA)        { h = 2; k = i - 2 * NA; }
    else if (i < 3 * NA + NB)   { h = 3; k = i - 3 * NA; }
    else if (i < 3 * NA + 2*NB) { h = 4; k = i - 3 * NA - NB; }
    else                        { h = 5; k = i - 3 * NA - 2 * NB; }
    const int Po[6] = {0, 1600000, 3200000, 4000000, 4320000, 4640000};
    const int Gn[6] = {32, 32, 16, 16, 16, 16};
    const int Kn[6] = {NA, NA, NA, NB, NB, NA};
    const int* p = P + Po[h] + k;
    int K = Kn[h], G = Gn[h], s = 0;
    for (int g = 0; g < G; ++g) s += p[g * K];
    ideg[i] = s;
    rdeg[i] = rsqrtf(fmaxf((float)s, 1.f));
}

// ---- 3-kernel exclusive scan over the 3 din arrays --------------------------
__global__ __launch_bounds__(256) void scan_reduce(
    const int* __restrict__ ideg, int* __restrict__ spart)
{
    __shared__ int lds[256];
    int y = blockIdx.y;
    const int off[3] = {NA, 3 * NA, 3 * NA + 2 * NB};
    const int nn[3]  = {NA, NB, NA};
    int n = nn[y];
    int b = blockIdx.x, t = threadIdx.x;
    if (b * 1024 >= n) return;
    const int* deg = ideg + off[y];
    int base = b * 1024 + t * 4;
    int s = 0;
    #pragma unroll
    for (int k = 0; k < 4; ++k) { int i = base + k; if (i < n) s += deg[i]; }
    lds[t] = s; __syncthreads();
    for (int o = 128; o > 0; o >>= 1) {
        if (t < o) lds[t] += lds[t + o];
        __syncthreads();
    }
    if (t == 0) spart[y * 64 + b] = lds[0];
}

__global__ void spine_kernel(int* __restrict__ spart) {   // block = 192
    int w = threadIdx.x >> 6, lane = threadIdx.x & 63;
    const int nblk[3] = {49, 20, 49};
    int n = nblk[w];
    int* p = spart + w * 64;
    int orig = (lane < n) ? p[lane] : 0;
    int v = orig;
    #pragma unroll
    for (int o = 1; o < 64; o <<= 1) {
        int u = __shfl_up(v, o);
        if (lane >= o) v += u;
    }
    if (lane < n) p[lane] = v - orig;
}

__global__ __launch_bounds__(256) void scan_final(
    const int* __restrict__ ideg, const int* __restrict__ spart,
    int* __restrict__ rp)
{
    __shared__ int lds[256];
    int y = blockIdx.y;
    const int off[3] = {NA, 3 * NA, 3 * NA + 2 * NB};
    const int nn[3]  = {NA, NB, NA};
    const int ro[3]  = {0, NA, NA + NB};
    int n = nn[y];
    int b = blockIdx.x, t = threadIdx.x;
    if (b * 1024 >= n) return;
    const int* deg = ideg + off[y];
    int* rowptr = rp + ro[y];
    int base = b * 1024 + t * 4;
    int v[4]; int tsum = 0;
    #pragma unroll
    for (int k = 0; k < 4; ++k) {
        v[k] = (base + k < n) ? deg[base + k] : 0;
        tsum += v[k];
    }
    lds[t] = tsum; __syncthreads();
    for (int o = 1; o < 256; o <<= 1) {
        int x = (t >= o) ? lds[t - o] : 0;
        __syncthreads();
        lds[t] += x;
        __syncthreads();
    }
    int run = lds[t] - tsum + spart[y * 64 + b];
    #pragma unroll
    for (int k = 0; k < 4; ++k) {
        if (base + k < n) rowptr[base + k] = run;
        run += v[k];
    }
}

// ---- din partials -> per-(group,key) exclusive global offsets, in place -----
__global__ __launch_bounds__(256) void offsets_kernel(
    int* __restrict__ P, const int* __restrict__ rp)
{
    int i = blockIdx.x * 256 + threadIdx.x;
    if (i >= 2 * NA + NB) return;
    int base, G, K, d, run;
    if (i < NA)           { base = 1600000; G = 32; K = NA; d = i;           run = rp[d]; }
    else if (i < NA + NB) { base = 4000000; G = 16; K = NB; d = i - NA;      run = rp[NA + d]; }
    else                  { base = 4640000; G = 16; K = NA; d = i - NA - NB; run = rp[NA + NB + d]; }
    int* p = P + base + d;
    for (int g = 0; g < G; ++g) {
        int t = p[g * K];
        p[g * K] = run;
        run += t;
    }
}

// ---- fully parallel placement: pos = offset[g][dst] + rank[e] ---------------
__global__ __launch_bounds__(512) void place_parallel(
    const int* __restrict__ s0, const int* __restrict__ d0,
    const int* __restrict__ s1, const int* __restrict__ d1,
    const int* __restrict__ s2, const int* __restrict__ d2,
    const int* __restrict__ P,
    const int* __restrict__ rank0, const int* __restrict__ rank1,
    const int* __restrict__ rank2,
    int* __restrict__ csr0, int* __restrict__ csr1, int* __restrict__ csr2)
{
    int z = blockIdx.z;
    const int En[3] = {NE0, NE1, NE2};
    const int Kn[3] = {NA, NB, NA};
    const int Po[3] = {1600000, 4000000, 4640000};
    int E = En[z], K = Kn[z];
    const int* src = z == 0 ? s0 : z == 1 ? s1 : s2;
    const int* dst = z == 0 ? d0 : z == 1 ? d1 : d2;
    const int* rk  = z == 0 ? rank0 : z == 1 ? rank1 : rank2;
    int* csr = z == 0 ? csr0 : z == 1 ? csr1 : csr2;
    const int* off = P + Po[z];
    int e = blockIdx.x * 512 + threadIdx.x;
    if (e >= E) return;
    int d = dst[e];
    int g = e / PER;
    int pos = off[g * K + d] + rk[e];
    csr[pos] = src[e];
}

// ---- W -> bf16 W^T ----------------------------------------------------------
__global__ __launch_bounds__(256) void wt_kernel(
    const float* __restrict__ W0, const float* __restrict__ W1,
    const float* __restrict__ W2, unsigned short* __restrict__ Wt)
{
    int i = blockIdx.x * 256 + threadIdx.x;
    if (i >= 3 * DD * DD) return;
    int w = i >> 14, r = i & (DD * DD - 1);
    int c = r >> 7, k = r & (DD - 1);
    const float* W = (w == 0) ? W0 : ((w == 1) ? W1 : W2);
    Wt[i] = f2bf(W[k * DD + c]);
}

// ---- fused MFMA GEMM (3 relations via blockIdx.z) ---------------------------
__global__ __launch_bounds__(256) void mfma_gemm(
    const float* __restrict__ hA, const float* __restrict__ hB,
    const unsigned short* __restrict__ Wt, const float* __restrict__ rdeg,
    unsigned short* __restrict__ mA0, unsigned short* __restrict__ mA1,
    unsigned short* __restrict__ mB2)
{
    int z = blockIdx.z;
    const float* X = (z == 2) ? hB : hA;
    const unsigned short* W = Wt + z * 16384;
    const float* rs = rdeg + (z == 0 ? 0 : z == 1 ? 2 * NA : 3 * NA + NB);
    unsigned short* M = z == 0 ? mA0 : z == 1 ? mA1 : mB2;
    int nrows = (z == 2) ? NB : NA;

    int wid  = threadIdx.x >> 6;
    int lane = threadIdx.x & 63;
    int quad = lane >> 4;
    int l16  = lane & 15;
    int base = blockIdx.x * 64 + wid * 16;
    if (base >= nrows) return;

    int arow = base + l16;
    if (arow >= nrows) arow = nrows - 1;
    bf16x8 a[4];
    #pragma unroll
    for (int kk = 0; kk < 4; ++kk) {
        const float4* p = (const float4*)(X + (size_t)arow * DD + kk * 32 + quad * 8);
        float4 u = p[0], w = p[1];
        bf16x8 t;
        t[0] = (short)f2bf(u.x); t[1] = (short)f2bf(u.y);
        t[2] = (short)f2bf(u.z); t[3] = (short)f2bf(u.w);
        t[4] = (short)f2bf(w.x); t[5] = (short)f2bf(w.y);
        t[6] = (short)f2bf(w.z); t[7] = (short)f2bf(w.w);
        a[kk] = t;
    }

    float rsv[4]; int orow0 = base + quad * 4;
    #pragma unroll
    for (int r = 0; r < 4; ++r) {
        int orow = orow0 + r;
        rsv[r] = rs[orow < nrows ? orow : 0];
    }

    #pragma unroll
    for (int ct = 0; ct < 8; ++ct) {
        f32x4 acc = {0.f, 0.f, 0.f, 0.f};
        const unsigned short* wp = W + (size_t)(ct * 16 + l16) * DD + quad * 8;
        #pragma unroll
        for (int kk = 0; kk < 4; ++kk) {
            bf16x8 b = *(const bf16x8*)(wp + kk * 32);
            acc = __builtin_amdgcn_mfma_f32_16x16x32_bf16(a[kk], b, acc, 0, 0, 0);
        }
        #pragma unroll
        for (int r = 0; r < 4; ++r) {
            int orow = orow0 + r;
            if (orow < nrows)
                M[(size_t)orow * DD + ct * 16 + l16] = f2bf(acc[r] * rsv[r]);
        }
    }
}

// ---- gather aggregation: one wave per dst row -------------------------------
__global__ __launch_bounds__(256) void gather_A(
    const unsigned short* __restrict__ mA0, const unsigned short* __restrict__ mB2,
    const int* __restrict__ csr0, const int* __restrict__ rp0, const int* __restrict__ dg0,
    const int* __restrict__ csr2, const int* __restrict__ rp2, const int* __restrict__ dg2,
    const float* __restrict__ rdin0, const float* __restrict__ rdin2,
    const float* __restrict__ b0, const float* __restrict__ b2,
    float* __restrict__ out)
{
    int wid = threadIdx.x >> 6, lane = threadIdx.x & 63;
    int d = blockIdx.x * 4 + wid;
    if (d >= NA) return;

    float a0 = 0.f, a1 = 0.f;
    {
        int st = rp0[d], n = dg0[d], i = 0;
        for (; i + 1 < n; i += 2) {
            int sA = csr0[st + i], sB = csr0[st + i + 1];
            unsigned int uA = *(const unsigned int*)(mA0 + (size_t)sA * DD + lane * 2);
            unsigned int uB = *(const unsigned int*)(mA0 + (size_t)sB * DD + lane * 2);
            a0 += bf2f(uA & 0xffff) + bf2f(uB & 0xffff);
            a1 += bf2f(uA >> 16)    + bf2f(uB >> 16);
        }
        if (i < n) {
            int s = csr0[st + i];
            unsigned int u = *(const unsigned int*)(mA0 + (size_t)s * DD + lane * 2);
            a0 += bf2f(u & 0xffff); a1 += bf2f(u >> 16);
        }
    }
    float c0 = 0.f, c1 = 0.f;
    {
        int st = rp2[d], n = dg2[d], i = 0;
        for (; i + 1 < n; i += 2) {
            int sA = csr2[st + i], sB = csr2[st + i + 1];
            unsigned int uA = *(const unsigned int*)(mB2 + (size_t)sA * DD + lane * 2);
            unsigned int uB = *(const unsigned int*)(mB2 + (size_t)sB * DD + lane * 2);
            c0 += bf2f(uA & 0xffff) + bf2f(uB & 0xffff);
            c1 += bf2f(uA >> 16)    + bf2f(uB >> 16);
        }
        if (i < n) {
            int s = csr2[st + i];
            unsigned int u = *(const unsigned int*)(mB2 + (size_t)s * DD + lane * 2);
            c0 += bf2f(u & 0xffff); c1 += bf2f(u >> 16);
        }
    }
    float r0 = rdin0[d], r2 = rdin2[d];
    int col = lane * 2;
    float2 o;
    o.x = a0 * r0 + c0 * r2 + b0[col]     + b2[col];
    o.y = a1 * r0 + c1 * r2 + b0[col + 1] + b2[col + 1];
    *(float2*)(out + (size_t)d * DD + col) = o;
}

__global__ __launch_bounds__(256) void gather_B(
    const unsigned short* __restrict__ mA1,
    const int* __restrict__ csr1, const int* __restrict__ rp1, const int* __restrict__ dg1,
    const float* __restrict__ rdin1, const float* __restrict__ b1,
    float* __restrict__ out)
{
    int wid = threadIdx.x >> 6, lane = threadIdx.x & 63;
    int d = blockIdx.x * 4 + wid;
    if (d >= NB) return;

    float a0 = 0.f, a1 = 0.f;
    int st = rp1[d], n = dg1[d], i = 0;
    for (; i + 1 < n; i += 2) {
        int sA = csr1[st + i], sB = csr1[st + i + 1];
        unsigned int uA = *(const unsigned int*)(mA1 + (size_t)sA * DD + lane * 2);
        unsigned int uB = *(const unsigned int*)(mA1 + (size_t)sB * DD + lane * 2);
        a0 += bf2f(uA & 0xffff) + bf2f(uB & 0xffff);
        a1 += bf2f(uA >> 16)    + bf2f(uB >> 16);
    }
    if (i < n) {
        int s = csr1[st + i];
        unsigned int u = *(const unsigned int*)(mA1 + (size_t)s * DD + lane * 2);
        a0 += bf2f(u & 0xffff); a1 += bf2f(u >> 16);
    }
    float r1 = rdin1[d];
    int col = lane * 2;
    float2 o;
    o.x = a0 * r1 + b1[col];
    o.y = a1 * r1 + b1[col + 1];
    *(float2*)(out + (size_t)d * DD + col) = o;
}

extern "C" void kernel_launch(void* const* d_in, const int* in_sizes, int n_in,
                              void* d_out, int out_size, void* d_ws, size_t ws_size,
                              hipStream_t stream) {
    const float* hA = (const float*)d_in[0];
    const float* hB = (const float*)d_in[1];
    const float* W0 = (const float*)d_in[2];
    const float* b0 = (const float*)d_in[3];
    const float* W1 = (const float*)d_in[4];
    const float* b1 = (const float*)d_in[5];
    const float* W2 = (const float*)d_in[6];
    const float* b2 = (const float*)d_in[7];
    const int* s0 = (const int*)d_in[8];
    const int* d0 = (const int*)d_in[9];
    const int* s1 = (const int*)d_in[10];
    const int* d1 = (const int*)d_in[11];
    const int* s2 = (const int*)d_in[12];
    const int* d2 = (const int*)d_in[13];
    float* out = (float*)d_out;
    char* ws = (char*)d_ws;

    // ws layout. P (21.76 MB) aliases mA0/mA1: P is dead before mfma_gemm runs.
    unsigned short* mA0 = (unsigned short*)(ws + 0);          // 12.8 MB
    unsigned short* mA1 = (unsigned short*)(ws + 12800000);   // 12.8 MB
    unsigned short* mB2 = (unsigned short*)(ws + 25600000);   // 5.12 MB
    int*   P            = (int*)  (ws + 0);                   // 21.76 MB (aliases mA0/mA1)
    unsigned short* Wt  = (unsigned short*)(ws + 30720000);   // 96 KB
    float* rdeg         = (float*)(ws + 30818304);            // 960 KB
    int*   ideg         = (int*)  (ws + 31778304);            // 960 KB
    int*   rp           = (int*)  (ws + 32738304);            // 480 KB
    int*   spart        = (int*)  (ws + 33218304);            // 1 KB
    int*   rank0        = (int*)  (ws + 33219328);            // 2.4 MB
    int*   rank1        = (int*)  (ws + 35619328);            // 1.2 MB
    int*   rank2        = (int*)  (ws + 36819328);            // 1.2 MB
    int*   csr0         = (int*)  (ws + 38019328);            // 2.4 MB
    int*   csr1         = (int*)  (ws + 40419328);            // 1.2 MB
    int*   csr2         = (int*)  (ws + 41619328);            // 1.2 MB

    const int* din0 = ideg + NA;
    const int* din1 = ideg + 3 * NA;
    const int* din2 = ideg + 3 * NA + 2 * NB;
    const float* rdin0 = rdeg + NA;
    const float* rdin1 = rdeg + 3 * NA;
    const float* rdin2 = rdeg + 3 * NA + 2 * NB;

    hist_kernel<<<dim3(4, 32, 6), 512, 0, stream>>>(s0, d0, s1, d1, s2, d2,
                                                    P, rank0, rank1, rank2);
    reduce_kernel<<<(DEG_TOT + 255) / 256, 256, 0, stream>>>(P, ideg, rdeg);

    scan_reduce<<<dim3(49, 3), 256, 0, stream>>>(ideg, spart);
    spine_kernel<<<1, 192, 0, stream>>>(spart);
    scan_final<<<dim3(49, 3), 256, 0, stream>>>(ideg, spart, rp);

    offsets_kernel<<<(2 * NA + NB + 255) / 256, 256, 0, stream>>>(P, rp);
    place_parallel<<<dim3((NE0 + 511) / 512, 1, 3), 512, 0, stream>>>(
        s0, d0, s1, d1, s2, d2, P, rank0, rank1, rank2, csr0, csr1, csr2);

    wt_kernel<<<(3 * DD * DD + 255) / 256, 256, 0, stream>>>(W0, W1, W2, Wt);
    mfma_gemm<<<dim3((NA + 63) / 64, 1, 3), 256, 0, stream>>>(hA, hB, Wt, rdeg,
                                                              mA0, mA1, mB2);

    gather_A<<<(NA + 3) / 4, 256, 0, stream>>>(mA0, mB2,
        csr0, rp, din0, csr2, rp + NA + NB, din2, rdin0, rdin2, b0, b2, out);
    gather_B<<<(NB + 3) / 4, 256, 0, stream>>>(mA1,
        csr1, rp + NA, din1, rdin1, b1, out + (size_t)NA * DD);
}

// Round 5
// 286.580 us; speedup vs baseline: 8.0679x; 1.0722x over previous
//
#include <hip/hip_runtime.h>

#define NA 50000
#define NB 20000
#define NE0 600000
#define NE1 300000
#define NE2 300000
#define DD 128
#define DEG_TOT (4 * NA + 2 * NB)
#define SUB 16384     // LDS histogram subrange (64 KB)
#define PER 18750     // edges per group: NE0/32 = NE1/16 = NE2/16

// P partial layout (ints):
// cfg0 dout0 G=32,K=NA @0        ; cfg1 din0 G=32,K=NA @1600000
// cfg2 dout1 G=16,K=NA @3200000  ; cfg3 din1 G=16,K=NB @4000000
// cfg4 dout2 G=16,K=NB @4320000  ; cfg5 din2 G=16,K=NA @4640000
#define P_TOT 5440000

typedef short bf16x8 __attribute__((ext_vector_type(8)));
typedef float f32x4 __attribute__((ext_vector_type(4)));

__device__ __forceinline__ unsigned short f2bf(float f) {
    union { float f; unsigned int u; } v; v.f = f;
    unsigned int r = v.u + 0x7fffu + ((v.u >> 16) & 1u);   // RNE
    return (unsigned short)(r >> 16);
}
__device__ __forceinline__ float bf2f(unsigned int u16) {
    union { float f; unsigned int u; } v; v.u = u16 << 16;
    return v.f;
}

// ---- LDS-privatized histograms; din cfgs also record each edge's rank -------
__global__ __launch_bounds__(512) void hist_kernel(
    const int* __restrict__ s0, const int* __restrict__ d0,
    const int* __restrict__ s1, const int* __restrict__ d1,
    const int* __restrict__ s2, const int* __restrict__ d2,
    int* __restrict__ P,
    int* __restrict__ rank0, int* __restrict__ rank1, int* __restrict__ rank2)
{
    __shared__ int h[SUB];
    const int cfg = blockIdx.z;
    const int En[6] = {NE0, NE0, NE1, NE1, NE2, NE2};
    const int Kn[6] = {NA, NA, NA, NB, NB, NA};
    const int Gn[6] = {32, 32, 16, 16, 16, 16};
    const int Po[6] = {0, 1600000, 3200000, 4000000, 4320000, 4640000};
    int E = En[cfg], K = Kn[cfg], G = Gn[cfg];
    int sub = blockIdx.x, g = blockIdx.y;
    int nsub = (K + SUB - 1) / SUB;
    if (sub >= nsub || g >= G) return;
    const int* keys = cfg == 0 ? s0 : cfg == 1 ? d0 : cfg == 2 ? s1
                    : cfg == 3 ? d1 : cfg == 4 ? s2 : d2;
    int* rk = cfg == 1 ? rank0 : cfg == 3 ? rank1 : cfg == 5 ? rank2 : (int*)0;
    int lo = sub * SUB;
    int hi = min(K, lo + SUB);
    int cnt = hi - lo;
    for (int i = threadIdx.x; i < cnt; i += 512) h[i] = 0;
    __syncthreads();
    int e1 = min(E, g * PER + PER);
    for (int e = g * PER + threadIdx.x; e < e1; e += 512) {
        int k = keys[e];
        if (k >= lo && k < hi) {
            int r = atomicAdd(&h[k - lo], 1);
            if (rk) rk[e] = r;
        }
    }
    __syncthreads();
    int* outp = P + Po[cfg] + g * K + lo;
    for (int i = threadIdx.x; i < cnt; i += 512) outp[i] = h[i];
}

// ---- sum partials -> integer degree + rsqrt ---------------------------------
__global__ __launch_bounds__(256) void reduce_kernel(
    const int* __restrict__ P, int* __restrict__ ideg, float* __restrict__ rdeg)
{
    int i = blockIdx.x * 256 + threadIdx.x;
    if (i >= DEG_TOT) return;
    int h, k;
    if      (i < NA)            { h = 0; k = i; }
    else if (i < 2 * NA)        { h = 1; k = i - NA; }
    else if (i < 3 * NA)        { h = 2; k = i - 2 * NA; }
    else if (i < 3 * NA + NB)   { h = 3; k = i - 3 * NA; }
    else if (i < 3 * NA + 2*NB) { h = 4; k = i - 3 * NA - NB; }
    else                        { h = 5; k = i - 3 * NA - 2 * NB; }
    const int Po[6] = {0, 1600000, 3200000, 4000000, 4320000, 4640000};
    const int Gn[6] = {32, 32, 16, 16, 16, 16};
    const int Kn[6] = {NA, NA, NA, NB, NB, NA};
    const int* p = P + Po[h] + k;
    int K = Kn[h], G = Gn[h], s = 0;
    for (int g = 0; g < G; ++g) s += p[g * K];
    ideg[i] = s;
    rdeg[i] = rsqrtf(fmaxf((float)s, 1.f));
}

// ---- 3-kernel exclusive scan over the 3 din arrays --------------------------
__global__ __launch_bounds__(256) void scan_reduce(
    const int* __restrict__ ideg, int* __restrict__ spart)
{
    __shared__ int lds[256];
    int y = blockIdx.y;
    const int off[3] = {NA, 3 * NA, 3 * NA + 2 * NB};
    const int nn[3]  = {NA, NB, NA};
    int n = nn[y];
    int b = blockIdx.x, t = threadIdx.x;
    if (b * 1024 >= n) return;
    const int* deg = ideg + off[y];
    int base = b * 1024 + t * 4;
    int s = 0;
    #pragma unroll
    for (int k = 0; k < 4; ++k) { int i = base + k; if (i < n) s += deg[i]; }
    lds[t] = s; __syncthreads();
    for (int o = 128; o > 0; o >>= 1) {
        if (t < o) lds[t] += lds[t + o];
        __syncthreads();
    }
    if (t == 0) spart[y * 64 + b] = lds[0];
}

__global__ void spine_kernel(int* __restrict__ spart) {   // block = 192
    int w = threadIdx.x >> 6, lane = threadIdx.x & 63;
    const int nblk[3] = {49, 20, 49};
    int n = nblk[w];
    int* p = spart + w * 64;
    int orig = (lane < n) ? p[lane] : 0;
    int v = orig;
    #pragma unroll
    for (int o = 1; o < 64; o <<= 1) {
        int u = __shfl_up(v, o);
        if (lane >= o) v += u;
    }
    if (lane < n) p[lane] = v - orig;
}

__global__ __launch_bounds__(256) void scan_final(
    const int* __restrict__ ideg, const int* __restrict__ spart,
    int* __restrict__ rp)
{
    __shared__ int lds[256];
    int y = blockIdx.y;
    const int off[3] = {NA, 3 * NA, 3 * NA + 2 * NB};
    const int nn[3]  = {NA, NB, NA};
    const int ro[3]  = {0, NA, NA + NB};
    int n = nn[y];
    int b = blockIdx.x, t = threadIdx.x;
    if (b * 1024 >= n) return;
    const int* deg = ideg + off[y];
    int* rowptr = rp + ro[y];
    int base = b * 1024 + t * 4;
    int v[4]; int tsum = 0;
    #pragma unroll
    for (int k = 0; k < 4; ++k) {
        v[k] = (base + k < n) ? deg[base + k] : 0;
        tsum += v[k];
    }
    lds[t] = tsum; __syncthreads();
    for (int o = 1; o < 256; o <<= 1) {
        int x = (t >= o) ? lds[t - o] : 0;
        __syncthreads();
        lds[t] += x;
        __syncthreads();
    }
    int run = lds[t] - tsum + spart[y * 64 + b];
    #pragma unroll
    for (int k = 0; k < 4; ++k) {
        if (base + k < n) rowptr[base + k] = run;
        run += v[k];
    }
}

// ---- din partials -> per-(group,key) exclusive global offsets, in place -----
__global__ __launch_bounds__(256) void offsets_kernel(
    int* __restrict__ P, const int* __restrict__ rp)
{
    int i = blockIdx.x * 256 + threadIdx.x;
    if (i >= 2 * NA + NB) return;
    int base, G, K, d, run;
    if (i < NA)           { base = 1600000; G = 32; K = NA; d = i;           run = rp[d]; }
    else if (i < NA + NB) { base = 4000000; G = 16; K = NB; d = i - NA;      run = rp[NA + d]; }
    else                  { base = 4640000; G = 16; K = NA; d = i - NA - NB; run = rp[NA + NB + d]; }
    int* p = P + base + d;
    for (int g = 0; g < G; ++g) {
        int t = p[g * K];
        p[g * K] = run;
        run += t;
    }
}

// ---- fully parallel placement: pos = offset[g][dst] + rank[e] ---------------
__global__ __launch_bounds__(512) void place_parallel(
    const int* __restrict__ s0, const int* __restrict__ d0,
    const int* __restrict__ s1, const int* __restrict__ d1,
    const int* __restrict__ s2, const int* __restrict__ d2,
    const int* __restrict__ P,
    const int* __restrict__ rank0, const int* __restrict__ rank1,
    const int* __restrict__ rank2,
    int* __restrict__ csr0, int* __restrict__ csr1, int* __restrict__ csr2)
{
    int z = blockIdx.z;
    const int En[3] = {NE0, NE1, NE2};
    const int Kn[3] = {NA, NB, NA};
    const int Po[3] = {1600000, 4000000, 4640000};
    int E = En[z], K = Kn[z];
    const int* src = z == 0 ? s0 : z == 1 ? s1 : s2;
    const int* dst = z == 0 ? d0 : z == 1 ? d1 : d2;
    const int* rk  = z == 0 ? rank0 : z == 1 ? rank1 : rank2;
    int* csr = z == 0 ? csr0 : z == 1 ? csr1 : csr2;
    const int* off = P + Po[z];
    int e = blockIdx.x * 512 + threadIdx.x;
    if (e >= E) return;
    int d = dst[e];
    int g = e / PER;
    int pos = off[g * K + d] + rk[e];
    csr[pos] = src[e];
}

// ---- W -> bf16 W^T ----------------------------------------------------------
__global__ __launch_bounds__(256) void wt_kernel(
    const float* __restrict__ W0, const float* __restrict__ W1,
    const float* __restrict__ W2, unsigned short* __restrict__ Wt)
{
    int i = blockIdx.x * 256 + threadIdx.x;
    if (i >= 3 * DD * DD) return;
    int w = i >> 14, r = i & (DD * DD - 1);
    int c = r >> 7, k = r & (DD - 1);
    const float* W = (w == 0) ? W0 : ((w == 1) ? W1 : W2);
    Wt[i] = f2bf(W[k * DD + c]);
}

// ---- dual-W MFMA GEMM over hA: reads each A-frag once, computes W0 and W1 ---
__global__ __launch_bounds__(256) void mfma_gemmA(
    const float* __restrict__ hA, const unsigned short* __restrict__ Wt,
    const float* __restrict__ rdeg,
    unsigned short* __restrict__ mA0, unsigned short* __restrict__ mA1)
{
    int wid  = threadIdx.x >> 6;
    int lane = threadIdx.x & 63;
    int quad = lane >> 4;
    int l16  = lane & 15;
    int base = blockIdx.x * 64 + wid * 16;
    if (base >= NA) return;

    int arow = base + l16;
    if (arow >= NA) arow = NA - 1;
    bf16x8 a[4];
    #pragma unroll
    for (int kk = 0; kk < 4; ++kk) {
        const float4* p = (const float4*)(hA + (size_t)arow * DD + kk * 32 + quad * 8);
        float4 u = p[0], w = p[1];
        bf16x8 t;
        t[0] = (short)f2bf(u.x); t[1] = (short)f2bf(u.y);
        t[2] = (short)f2bf(u.z); t[3] = (short)f2bf(u.w);
        t[4] = (short)f2bf(w.x); t[5] = (short)f2bf(w.y);
        t[6] = (short)f2bf(w.z); t[7] = (short)f2bf(w.w);
        a[kk] = t;
    }

    float rs0[4], rs1[4]; int orow0 = base + quad * 4;
    #pragma unroll
    for (int r = 0; r < 4; ++r) {
        int orow = orow0 + r; int c = orow < NA ? orow : 0;
        rs0[r] = rdeg[c]; rs1[r] = rdeg[2 * NA + c];
    }

    #pragma unroll
    for (int ct = 0; ct < 8; ++ct) {
        f32x4 acc0 = {0.f, 0.f, 0.f, 0.f};
        f32x4 acc1 = {0.f, 0.f, 0.f, 0.f};
        const unsigned short* wp = Wt + (size_t)(ct * 16 + l16) * DD + quad * 8;
        #pragma unroll
        for (int kk = 0; kk < 4; ++kk) {
            bf16x8 b0 = *(const bf16x8*)(wp + kk * 32);
            bf16x8 b1 = *(const bf16x8*)(wp + 16384 + kk * 32);
            acc0 = __builtin_amdgcn_mfma_f32_16x16x32_bf16(a[kk], b0, acc0, 0, 0, 0);
            acc1 = __builtin_amdgcn_mfma_f32_16x16x32_bf16(a[kk], b1, acc1, 0, 0, 0);
        }
        #pragma unroll
        for (int r = 0; r < 4; ++r) {
            int orow = orow0 + r;
            if (orow < NA) {
                mA0[(size_t)orow * DD + ct * 16 + l16] = f2bf(acc0[r] * rs0[r]);
                mA1[(size_t)orow * DD + ct * 16 + l16] = f2bf(acc1[r] * rs1[r]);
            }
        }
    }
}

// ---- single-W MFMA GEMM over hB (W2) ----------------------------------------
__global__ __launch_bounds__(256) void mfma_gemmB(
    const float* __restrict__ hB, const unsigned short* __restrict__ Wt,
    const float* __restrict__ rdeg, unsigned short* __restrict__ mB2)
{
    int wid  = threadIdx.x >> 6;
    int lane = threadIdx.x & 63;
    int quad = lane >> 4;
    int l16  = lane & 15;
    int base = blockIdx.x * 64 + wid * 16;
    if (base >= NB) return;

    int arow = base + l16;
    if (arow >= NB) arow = NB - 1;
    bf16x8 a[4];
    #pragma unroll
    for (int kk = 0; kk < 4; ++kk) {
        const float4* p = (const float4*)(hB + (size_t)arow * DD + kk * 32 + quad * 8);
        float4 u = p[0], w = p[1];
        bf16x8 t;
        t[0] = (short)f2bf(u.x); t[1] = (short)f2bf(u.y);
        t[2] = (short)f2bf(u.z); t[3] = (short)f2bf(u.w);
        t[4] = (short)f2bf(w.x); t[5] = (short)f2bf(w.y);
        t[6] = (short)f2bf(w.z); t[7] = (short)f2bf(w.w);
        a[kk] = t;
    }

    float rs[4]; int orow0 = base + quad * 4;
    #pragma unroll
    for (int r = 0; r < 4; ++r) {
        int orow = orow0 + r;
        rs[r] = rdeg[3 * NA + NB + (orow < NB ? orow : 0)];
    }

    #pragma unroll
    for (int ct = 0; ct < 8; ++ct) {
        f32x4 acc = {0.f, 0.f, 0.f, 0.f};
        const unsigned short* wp = Wt + 32768 + (size_t)(ct * 16 + l16) * DD + quad * 8;
        #pragma unroll
        for (int kk = 0; kk < 4; ++kk) {
            bf16x8 b = *(const bf16x8*)(wp + kk * 32);
            acc = __builtin_amdgcn_mfma_f32_16x16x32_bf16(a[kk], b, acc, 0, 0, 0);
        }
        #pragma unroll
        for (int r = 0; r < 4; ++r) {
            int orow = orow0 + r;
            if (orow < NB)
                mB2[(size_t)orow * DD + ct * 16 + l16] = f2bf(acc[r] * rs[r]);
        }
    }
}

// ---- gather: indices pre-loaded into a register, rows fetched 4-wide --------
__device__ __forceinline__ void gather_rel(
    const unsigned short* __restrict__ M, const int* __restrict__ csr,
    int st, int n, int lane, float& o0, float& o1)
{
    for (int ch = 0; ch < n; ch += 64) {
        int m = min(64, n - ch);
        int idx = csr[st + ch + (lane < m ? lane : m - 1)];  // coalesced prefetch
        for (int j = 0; j < m; j += 4) {
            int sA = __shfl(idx, j);
            int sB = __shfl(idx, (j + 1 < m) ? j + 1 : j);
            int sC = __shfl(idx, (j + 2 < m) ? j + 2 : j);
            int sD = __shfl(idx, (j + 3 < m) ? j + 3 : j);
            float wB = (j + 1 < m) ? 1.f : 0.f;
            float wC = (j + 2 < m) ? 1.f : 0.f;
            float wD = (j + 3 < m) ? 1.f : 0.f;
            unsigned int uA = *(const unsigned int*)(M + (size_t)sA * DD + lane * 2);
            unsigned int uB = *(const unsigned int*)(M + (size_t)sB * DD + lane * 2);
            unsigned int uC = *(const unsigned int*)(M + (size_t)sC * DD + lane * 2);
            unsigned int uD = *(const unsigned int*)(M + (size_t)sD * DD + lane * 2);
            o0 += bf2f(uA & 0xffff);
            o1 += bf2f(uA >> 16);
            o0 = fmaf(wB, bf2f(uB & 0xffff), o0);
            o1 = fmaf(wB, bf2f(uB >> 16),    o1);
            o0 = fmaf(wC, bf2f(uC & 0xffff), o0);
            o1 = fmaf(wC, bf2f(uC >> 16),    o1);
            o0 = fmaf(wD, bf2f(uD & 0xffff), o0);
            o1 = fmaf(wD, bf2f(uD >> 16),    o1);
        }
    }
}

__global__ __launch_bounds__(256) void gather_A(
    const unsigned short* __restrict__ mA0, const unsigned short* __restrict__ mB2,
    const int* __restrict__ csr0, const int* __restrict__ rp0, const int* __restrict__ dg0,
    const int* __restrict__ csr2, const int* __restrict__ rp2, const int* __restrict__ dg2,
    const float* __restrict__ rdin0, const float* __restrict__ rdin2,
    const float* __restrict__ b0, const float* __restrict__ b2,
    float* __restrict__ out)
{
    int wid = threadIdx.x >> 6, lane = threadIdx.x & 63;
    int d = blockIdx.x * 4 + wid;
    if (d >= NA) return;

    float a0 = 0.f, a1 = 0.f, c0 = 0.f, c1 = 0.f;
    gather_rel(mA0, csr0, rp0[d], dg0[d], lane, a0, a1);
    gather_rel(mB2, csr2, rp2[d], dg2[d], lane, c0, c1);

    float r0 = rdin0[d], r2 = rdin2[d];
    int col = lane * 2;
    float2 o;
    o.x = a0 * r0 + c0 * r2 + b0[col]     + b2[col];
    o.y = a1 * r0 + c1 * r2 + b0[col + 1] + b2[col + 1];
    *(float2*)(out + (size_t)d * DD + col) = o;
}

__global__ __launch_bounds__(256) void gather_B(
    const unsigned short* __restrict__ mA1,
    const int* __restrict__ csr1, const int* __restrict__ rp1, const int* __restrict__ dg1,
    const float* __restrict__ rdin1, const float* __restrict__ b1,
    float* __restrict__ out)
{
    int wid = threadIdx.x >> 6, lane = threadIdx.x & 63;
    int d = blockIdx.x * 4 + wid;
    if (d >= NB) return;

    float a0 = 0.f, a1 = 0.f;
    gather_rel(mA1, csr1, rp1[d], dg1[d], lane, a0, a1);

    float r1 = rdin1[d];
    int col = lane * 2;
    float2 o;
    o.x = a0 * r1 + b1[col];
    o.y = a1 * r1 + b1[col + 1];
    *(float2*)(out + (size_t)d * DD + col) = o;
}

extern "C" void kernel_launch(void* const* d_in, const int* in_sizes, int n_in,
                              void* d_out, int out_size, void* d_ws, size_t ws_size,
                              hipStream_t stream) {
    const float* hA = (const float*)d_in[0];
    const float* hB = (const float*)d_in[1];
    const float* W0 = (const float*)d_in[2];
    const float* b0 = (const float*)d_in[3];
    const float* W1 = (const float*)d_in[4];
    const float* b1 = (const float*)d_in[5];
    const float* W2 = (const float*)d_in[6];
    const float* b2 = (const float*)d_in[7];
    const int* s0 = (const int*)d_in[8];
    const int* d0 = (const int*)d_in[9];
    const int* s1 = (const int*)d_in[10];
    const int* d1 = (const int*)d_in[11];
    const int* s2 = (const int*)d_in[12];
    const int* d2 = (const int*)d_in[13];
    float* out = (float*)d_out;
    char* ws = (char*)d_ws;

    // ws layout. P (21.76 MB) aliases mA0/mA1: P is dead before the GEMMs run.
    unsigned short* mA0 = (unsigned short*)(ws + 0);          // 12.8 MB
    unsigned short* mA1 = (unsigned short*)(ws + 12800000);   // 12.8 MB
    unsigned short* mB2 = (unsigned short*)(ws + 25600000);   // 5.12 MB
    int*   P            = (int*)  (ws + 0);                   // 21.76 MB (aliases mA0/mA1)
    unsigned short* Wt  = (unsigned short*)(ws + 30720000);   // 96 KB
    float* rdeg         = (float*)(ws + 30818304);            // 960 KB
    int*   ideg         = (int*)  (ws + 31778304);            // 960 KB
    int*   rp           = (int*)  (ws + 32738304);            // 480 KB
    int*   spart        = (int*)  (ws + 33218304);            // 1 KB
    int*   rank0        = (int*)  (ws + 33219328);            // 2.4 MB
    int*   rank1        = (int*)  (ws + 35619328);            // 1.2 MB
    int*   rank2        = (int*)  (ws + 36819328);            // 1.2 MB
    int*   csr0         = (int*)  (ws + 38019328);            // 2.4 MB
    int*   csr1         = (int*)  (ws + 40419328);            // 1.2 MB
    int*   csr2         = (int*)  (ws + 41619328);            // 1.2 MB

    const int* din0 = ideg + NA;
    const int* din1 = ideg + 3 * NA;
    const int* din2 = ideg + 3 * NA + 2 * NB;
    const float* rdin0 = rdeg + NA;
    const float* rdin1 = rdeg + 3 * NA;
    const float* rdin2 = rdeg + 3 * NA + 2 * NB;

    hist_kernel<<<dim3(4, 32, 6), 512, 0, stream>>>(s0, d0, s1, d1, s2, d2,
                                                    P, rank0, rank1, rank2);
    reduce_kernel<<<(DEG_TOT + 255) / 256, 256, 0, stream>>>(P, ideg, rdeg);

    scan_reduce<<<dim3(49, 3), 256, 0, stream>>>(ideg, spart);
    spine_kernel<<<1, 192, 0, stream>>>(spart);
    scan_final<<<dim3(49, 3), 256, 0, stream>>>(ideg, spart, rp);

    offsets_kernel<<<(2 * NA + NB + 255) / 256, 256, 0, stream>>>(P, rp);
    place_parallel<<<dim3((NE0 + 511) / 512, 1, 3), 512, 0, stream>>>(
        s0, d0, s1, d1, s2, d2, P, rank0, rank1, rank2, csr0, csr1, csr2);

    wt_kernel<<<(3 * DD * DD + 255) / 256, 256, 0, stream>>>(W0, W1, W2, Wt);
    mfma_gemmA<<<(NA + 63) / 64, 256, 0, stream>>>(hA, Wt, rdeg, mA0, mA1);
    mfma_gemmB<<<(NB + 63) / 64, 256, 0, stream>>>(hB, Wt, rdeg, mB2);

    gather_A<<<(NA + 3) / 4, 256, 0, stream>>>(mA0, mB2,
        csr0, rp, din0, csr2, rp + NA + NB, din2, rdin0, rdin2, b0, b2, out);
    gather_B<<<(NB + 3) / 4, 256, 0, stream>>>(mA1,
        csr1, rp + NA, din1, rdin1, b1, out + (size_t)NA * DD);
}

// Round 6
// 264.709 us; speedup vs baseline: 8.7345x; 1.0826x over previous
//
#include <hip/hip_runtime.h>

#define NA 50000
#define NB 20000
#define NE0 600000
#define NE1 300000
#define NE2 300000
#define DD 128
#define DEG_TOT (4 * NA + 2 * NB)
#define SUB 32768     // keys per LDS histogram pass (16-bit packed counters, 64 KB)
#define PER 18750     // edges per group: NE0/32 = NE1/16 = NE2/16

// P packed-ushort cell layout (cell index = Po[cfg] + g*K + k):
// cfg0 dout0 G=32,K=NA @0        ; cfg1 din0 G=32,K=NA @1600000
// cfg2 dout1 G=16,K=NA @3200000  ; cfg3 din1 G=16,K=NB @4000000
// cfg4 dout2 G=16,K=NB @4320000  ; cfg5 din2 G=16,K=NA @4640000
// O int layout (din offsets): O1 @0 (32*NA) ; O3 @1600000 (16*NB) ; O5 @1920000 (16*NA)

typedef short bf16x8 __attribute__((ext_vector_type(8)));
typedef float f32x4 __attribute__((ext_vector_type(4)));

__device__ __forceinline__ unsigned short f2bf(float f) {
    union { float f; unsigned int u; } v; v.f = f;
    unsigned int r = v.u + 0x7fffu + ((v.u >> 16) & 1u);   // RNE
    return (unsigned short)(r >> 16);
}
__device__ __forceinline__ float bf2f(unsigned int u16) {
    union { float f; unsigned int u; } v; v.u = u16 << 16;
    return v.f;
}
__device__ __forceinline__ float lo2f(unsigned int u) {    // low bf16 of dword
    union { float f; unsigned int u; } v; v.u = u << 16;
    return v.f;
}
__device__ __forceinline__ float hi2f(unsigned int u) {    // high bf16 of dword
    union { float f; unsigned int u; } v; v.u = u & 0xffff0000u;
    return v.f;
}

// ---- LDS histograms, 16-bit packed counters; din cfgs record per-edge rank --
__global__ __launch_bounds__(1024) void hist_kernel(
    const int* __restrict__ s0, const int* __restrict__ d0,
    const int* __restrict__ s1, const int* __restrict__ d1,
    const int* __restrict__ s2, const int* __restrict__ d2,
    unsigned int* __restrict__ Pd,   // dword view of packed P
    int* __restrict__ rank0, int* __restrict__ rank1, int* __restrict__ rank2)
{
    __shared__ unsigned int h32[SUB / 2];
    const int cfg = blockIdx.z;
    const int En[6] = {NE0, NE0, NE1, NE1, NE2, NE2};
    const int Kn[6] = {NA, NA, NA, NB, NB, NA};
    const int Gn[6] = {32, 32, 16, 16, 16, 16};
    const int Po[6] = {0, 1600000, 3200000, 4000000, 4320000, 4640000};
    int E = En[cfg], K = Kn[cfg], G = Gn[cfg];
    int sub = blockIdx.x, g = blockIdx.y;
    int nsub = (K + SUB - 1) / SUB;
    if (sub >= nsub || g >= G) return;
    const int* keys = cfg == 0 ? s0 : cfg == 1 ? d0 : cfg == 2 ? s1
                    : cfg == 3 ? d1 : cfg == 4 ? s2 : d2;
    int* rk = cfg == 1 ? rank0 : cfg == 3 ? rank1 : cfg == 5 ? rank2 : (int*)0;
    int lo = sub * SUB;                 // even
    int hi = min(K, lo + SUB);
    int cnt = hi - lo;                  // even for all cfgs here
    for (int i = threadIdx.x; i < SUB / 2; i += 1024) h32[i] = 0;
    __syncthreads();
    int e1 = min(E, g * PER + PER);
    for (int e = g * PER + threadIdx.x; e < e1; e += 1024) {
        int k = keys[e];
        if (k >= lo && k < hi) {
            int kk = k - lo;
            unsigned sh = (kk & 1) << 4;
            unsigned old = atomicAdd(&h32[kk >> 1], 1u << sh);
            if (rk) rk[e] = (int)((old >> sh) & 0xffffu);
        }
    }
    __syncthreads();
    unsigned int* outp = Pd + ((Po[cfg] + g * K + lo) >> 1);
    for (int i = threadIdx.x; i < cnt / 2; i += 1024) outp[i] = h32[i];
}

// ---- sum packed partials -> integer degree + rsqrt --------------------------
__global__ __launch_bounds__(256) void reduce_kernel(
    const unsigned short* __restrict__ P16, int* __restrict__ ideg,
    float* __restrict__ rdeg)
{
    int i = blockIdx.x * 256 + threadIdx.x;
    if (i >= DEG_TOT) return;
    int h, k;
    if      (i < NA)            { h = 0; k = i; }
    else if (i < 2 * NA)        { h = 1; k = i - NA; }
    else if (i < 3 * NA)        { h = 2; k = i - 2 * NA; }
    else if (i < 3 * NA + NB)   { h = 3; k = i - 3 * NA; }
    else if (i < 3 * NA + 2*NB) { h = 4; k = i - 3 * NA - NB; }
    else                        { h = 5; k = i - 3 * NA - 2 * NB; }
    const int Po[6] = {0, 1600000, 3200000, 4000000, 4320000, 4640000};
    const int Gn[6] = {32, 32, 16, 16, 16, 16};
    const int Kn[6] = {NA, NA, NA, NB, NB, NA};
    const unsigned short* p = P16 + Po[h] + k;
    int K = Kn[h], G = Gn[h], s = 0;
    for (int g = 0; g < G; ++g) s += p[g * K];
    ideg[i] = s;
    rdeg[i] = rsqrtf(fmaxf((float)s, 1.f));
}

// ---- 3-kernel exclusive scan over the 3 din arrays --------------------------
__global__ __launch_bounds__(256) void scan_reduce(
    const int* __restrict__ ideg, int* __restrict__ spart)
{
    __shared__ int lds[256];
    int y = blockIdx.y;
    const int off[3] = {NA, 3 * NA, 3 * NA + 2 * NB};
    const int nn[3]  = {NA, NB, NA};
    int n = nn[y];
    int b = blockIdx.x, t = threadIdx.x;
    if (b * 1024 >= n) return;
    const int* deg = ideg + off[y];
    int base = b * 1024 + t * 4;
    int s = 0;
    #pragma unroll
    for (int k = 0; k < 4; ++k) { int i = base + k; if (i < n) s += deg[i]; }
    lds[t] = s; __syncthreads();
    for (int o = 128; o > 0; o >>= 1) {
        if (t < o) lds[t] += lds[t + o];
        __syncthreads();
    }
    if (t == 0) spart[y * 64 + b] = lds[0];
}

__global__ void spine_kernel(int* __restrict__ spart) {   // block = 192
    int w = threadIdx.x >> 6, lane = threadIdx.x & 63;
    const int nblk[3] = {49, 20, 49};
    int n = nblk[w];
    int* p = spart + w * 64;
    int orig = (lane < n) ? p[lane] : 0;
    int v = orig;
    #pragma unroll
    for (int o = 1; o < 64; o <<= 1) {
        int u = __shfl_up(v, o);
        if (lane >= o) v += u;
    }
    if (lane < n) p[lane] = v - orig;
}

__global__ __launch_bounds__(256) void scan_final(
    const int* __restrict__ ideg, const int* __restrict__ spart,
    int* __restrict__ rp)
{
    __shared__ int lds[256];
    int y = blockIdx.y;
    const int off[3] = {NA, 3 * NA, 3 * NA + 2 * NB};
    const int nn[3]  = {NA, NB, NA};
    const int ro[3]  = {0, NA, NA + NB};
    int n = nn[y];
    int b = blockIdx.x, t = threadIdx.x;
    if (b * 1024 >= n) return;
    const int* deg = ideg + off[y];
    int* rowptr = rp + ro[y];
    int base = b * 1024 + t * 4;
    int v[4]; int tsum = 0;
    #pragma unroll
    for (int k = 0; k < 4; ++k) {
        v[k] = (base + k < n) ? deg[base + k] : 0;
        tsum += v[k];
    }
    lds[t] = tsum; __syncthreads();
    for (int o = 1; o < 256; o <<= 1) {
        int x = (t >= o) ? lds[t - o] : 0;
        __syncthreads();
        lds[t] += x;
        __syncthreads();
    }
    int run = lds[t] - tsum + spart[y * 64 + b];
    #pragma unroll
    for (int k = 0; k < 4; ++k) {
        if (base + k < n) rowptr[base + k] = run;
        run += v[k];
    }
}

// ---- packed din counts -> per-(group,key) exclusive global int offsets ------
__global__ __launch_bounds__(256) void offsets_kernel(
    const unsigned short* __restrict__ P16, const int* __restrict__ rp,
    int* __restrict__ O)
{
    int i = blockIdx.x * 256 + threadIdx.x;
    if (i >= 2 * NA + NB) return;
    int pbase, obase, G, K, d, run;
    if (i < NA)           { pbase = 1600000; obase = 0;       G = 32; K = NA; d = i;           run = rp[d]; }
    else if (i < NA + NB) { pbase = 4000000; obase = 1600000; G = 16; K = NB; d = i - NA;      run = rp[NA + d]; }
    else                  { pbase = 4640000; obase = 1920000; G = 16; K = NA; d = i - NA - NB; run = rp[NA + NB + d]; }
    const unsigned short* p = P16 + pbase + d;
    int* o = O + obase + d;
    for (int g = 0; g < G; ++g) {
        int t = p[g * K];
        o[g * K] = run;
        run += t;
    }
}

// ---- fully parallel placement: pos = O[g][dst] + rank[e] --------------------
__global__ __launch_bounds__(512) void place_parallel(
    const int* __restrict__ s0, const int* __restrict__ d0,
    const int* __restrict__ s1, const int* __restrict__ d1,
    const int* __restrict__ s2, const int* __restrict__ d2,
    const int* __restrict__ O,
    const int* __restrict__ rank0, const int* __restrict__ rank1,
    const int* __restrict__ rank2,
    int* __restrict__ csr0, int* __restrict__ csr1, int* __restrict__ csr2)
{
    int z = blockIdx.z;
    const int En[3] = {NE0, NE1, NE2};
    const int Kn[3] = {NA, NB, NA};
    const int Oo[3] = {0, 1600000, 1920000};
    int E = En[z], K = Kn[z];
    const int* src = z == 0 ? s0 : z == 1 ? s1 : s2;
    const int* dst = z == 0 ? d0 : z == 1 ? d1 : d2;
    const int* rk  = z == 0 ? rank0 : z == 1 ? rank1 : rank2;
    int* csr = z == 0 ? csr0 : z == 1 ? csr1 : csr2;
    const int* off = O + Oo[z];
    int e = blockIdx.x * 512 + threadIdx.x;
    if (e >= E) return;
    int d = dst[e];
    int g = e / PER;
    int pos = off[g * K + d] + rk[e];
    csr[pos] = src[e];
}

// ---- W -> bf16 W^T ----------------------------------------------------------
__global__ __launch_bounds__(256) void wt_kernel(
    const float* __restrict__ W0, const float* __restrict__ W1,
    const float* __restrict__ W2, unsigned short* __restrict__ Wt)
{
    int i = blockIdx.x * 256 + threadIdx.x;
    if (i >= 3 * DD * DD) return;
    int w = i >> 14, r = i & (DD * DD - 1);
    int c = r >> 7, k = r & (DD - 1);
    const float* W = (w == 0) ? W0 : ((w == 1) ? W1 : W2);
    Wt[i] = f2bf(W[k * DD + c]);
}

// ---- fused GEMMs: blocks [0,782) dual-W over hA; [782,1095) W2 over hB ------
__global__ __launch_bounds__(256) void gemm_all(
    const float* __restrict__ hA, const float* __restrict__ hB,
    const unsigned short* __restrict__ Wt, const float* __restrict__ rdeg,
    unsigned short* __restrict__ mA0, unsigned short* __restrict__ mA1,
    unsigned short* __restrict__ mB2)
{
    int wid  = threadIdx.x >> 6;
    int lane = threadIdx.x & 63;
    int quad = lane >> 4;
    int l16  = lane & 15;

    if (blockIdx.x < 782) {
        int base = blockIdx.x * 64 + wid * 16;
        if (base >= NA) return;
        int arow = base + l16;
        if (arow >= NA) arow = NA - 1;
        bf16x8 a[4];
        #pragma unroll
        for (int kk = 0; kk < 4; ++kk) {
            const float4* p = (const float4*)(hA + (size_t)arow * DD + kk * 32 + quad * 8);
            float4 u = p[0], w = p[1];
            bf16x8 t;
            t[0] = (short)f2bf(u.x); t[1] = (short)f2bf(u.y);
            t[2] = (short)f2bf(u.z); t[3] = (short)f2bf(u.w);
            t[4] = (short)f2bf(w.x); t[5] = (short)f2bf(w.y);
            t[6] = (short)f2bf(w.z); t[7] = (short)f2bf(w.w);
            a[kk] = t;
        }
        float rs0[4], rs1[4]; int orow0 = base + quad * 4;
        #pragma unroll
        for (int r = 0; r < 4; ++r) {
            int orow = orow0 + r; int c = orow < NA ? orow : 0;
            rs0[r] = rdeg[c]; rs1[r] = rdeg[2 * NA + c];
        }
        #pragma unroll
        for (int ct = 0; ct < 8; ++ct) {
            f32x4 acc0 = {0.f, 0.f, 0.f, 0.f};
            f32x4 acc1 = {0.f, 0.f, 0.f, 0.f};
            const unsigned short* wp = Wt + (size_t)(ct * 16 + l16) * DD + quad * 8;
            #pragma unroll
            for (int kk = 0; kk < 4; ++kk) {
                bf16x8 b0 = *(const bf16x8*)(wp + kk * 32);
                bf16x8 b1 = *(const bf16x8*)(wp + 16384 + kk * 32);
                acc0 = __builtin_amdgcn_mfma_f32_16x16x32_bf16(a[kk], b0, acc0, 0, 0, 0);
                acc1 = __builtin_amdgcn_mfma_f32_16x16x32_bf16(a[kk], b1, acc1, 0, 0, 0);
            }
            #pragma unroll
            for (int r = 0; r < 4; ++r) {
                int orow = orow0 + r;
                if (orow < NA) {
                    mA0[(size_t)orow * DD + ct * 16 + l16] = f2bf(acc0[r] * rs0[r]);
                    mA1[(size_t)orow * DD + ct * 16 + l16] = f2bf(acc1[r] * rs1[r]);
                }
            }
        }
    } else {
        int base = (blockIdx.x - 782) * 64 + wid * 16;
        if (base >= NB) return;
        int arow = base + l16;
        if (arow >= NB) arow = NB - 1;
        bf16x8 a[4];
        #pragma unroll
        for (int kk = 0; kk < 4; ++kk) {
            const float4* p = (const float4*)(hB + (size_t)arow * DD + kk * 32 + quad * 8);
            float4 u = p[0], w = p[1];
            bf16x8 t;
            t[0] = (short)f2bf(u.x); t[1] = (short)f2bf(u.y);
            t[2] = (short)f2bf(u.z); t[3] = (short)f2bf(u.w);
            t[4] = (short)f2bf(w.x); t[5] = (short)f2bf(w.y);
            t[6] = (short)f2bf(w.z); t[7] = (short)f2bf(w.w);
            a[kk] = t;
        }
        float rs[4]; int orow0 = base + quad * 4;
        #pragma unroll
        for (int r = 0; r < 4; ++r) {
            int orow = orow0 + r;
            rs[r] = rdeg[3 * NA + NB + (orow < NB ? orow : 0)];
        }
        #pragma unroll
        for (int ct = 0; ct < 8; ++ct) {
            f32x4 acc = {0.f, 0.f, 0.f, 0.f};
            const unsigned short* wp = Wt + 32768 + (size_t)(ct * 16 + l16) * DD + quad * 8;
            #pragma unroll
            for (int kk = 0; kk < 4; ++kk) {
                bf16x8 b = *(const bf16x8*)(wp + kk * 32);
                acc = __builtin_amdgcn_mfma_f32_16x16x32_bf16(a[kk], b, acc, 0, 0, 0);
            }
            #pragma unroll
            for (int r = 0; r < 4; ++r) {
                int orow = orow0 + r;
                if (orow < NB)
                    mB2[(size_t)orow * DD + ct * 16 + l16] = f2bf(acc[r] * rs[r]);
            }
        }
    }
}

// ---- lean gather: 32-bit saddr offsets, pure unpack+add main loop -----------
__device__ __forceinline__ void gather_rel(
    const char* __restrict__ Mb, const int* __restrict__ csr,
    int st, int n, int lane, unsigned laneoff, float& o0, float& o1)
{
    for (int ch = 0; ch < n; ch += 64) {
        int m = n - ch; if (m > 64) m = 64;
        int idx = csr[st + ch + (lane < m ? lane : m - 1)];  // coalesced prefetch
        int j = 0;
        for (; j + 4 <= m; j += 4) {
            int sA = __shfl(idx, j);
            int sB = __shfl(idx, j + 1);
            int sC = __shfl(idx, j + 2);
            int sD = __shfl(idx, j + 3);
            unsigned uA = *(const unsigned*)(Mb + (((unsigned)sA << 8) + laneoff));
            unsigned uB = *(const unsigned*)(Mb + (((unsigned)sB << 8) + laneoff));
            unsigned uC = *(const unsigned*)(Mb + (((unsigned)sC << 8) + laneoff));
            unsigned uD = *(const unsigned*)(Mb + (((unsigned)sD << 8) + laneoff));
            o0 += lo2f(uA); o1 += hi2f(uA);
            o0 += lo2f(uB); o1 += hi2f(uB);
            o0 += lo2f(uC); o1 += hi2f(uC);
            o0 += lo2f(uD); o1 += hi2f(uD);
        }
        for (; j < m; ++j) {
            int s = __shfl(idx, j);
            unsigned u = *(const unsigned*)(Mb + (((unsigned)s << 8) + laneoff));
            o0 += lo2f(u); o1 += hi2f(u);
        }
    }
}

// ---- fused gather: blocks [0,12500) -> out_A rows; [12500,17500) -> out_B ---
__global__ __launch_bounds__(256) void gather_all(
    const unsigned short* __restrict__ mA0, const unsigned short* __restrict__ mA1,
    const unsigned short* __restrict__ mB2,
    const int* __restrict__ csr0, const int* __restrict__ csr1,
    const int* __restrict__ csr2,
    const int* __restrict__ rp, const int* __restrict__ ideg,
    const float* __restrict__ rdeg,
    const float* __restrict__ b0, const float* __restrict__ b1,
    const float* __restrict__ b2,
    float* __restrict__ out)
{
    int wid = threadIdx.x >> 6, lane = threadIdx.x & 63;
    unsigned laneoff = (unsigned)lane * 4u;
    int col = lane * 2;

    if (blockIdx.x < 12500) {
        int d = blockIdx.x * 4 + wid;   // always < NA
        float a0 = 0.f, a1 = 0.f, c0 = 0.f, c1 = 0.f;
        gather_rel((const char*)mA0, csr0, rp[d], ideg[NA + d], lane, laneoff, a0, a1);
        gather_rel((const char*)mB2, csr2, rp[NA + NB + d], ideg[3 * NA + 2 * NB + d],
                   lane, laneoff, c0, c1);
        float r0 = rdeg[NA + d], r2 = rdeg[3 * NA + 2 * NB + d];
        float2 o;
        o.x = a0 * r0 + c0 * r2 + b0[col]     + b2[col];
        o.y = a1 * r0 + c1 * r2 + b0[col + 1] + b2[col + 1];
        *(float2*)(out + (size_t)d * DD + col) = o;
    } else {
        int d = (blockIdx.x - 12500) * 4 + wid;   // always < NB
        float a0 = 0.f, a1 = 0.f;
        gather_rel((const char*)mA1, csr1, rp[NA + d], ideg[3 * NA + d],
                   lane, laneoff, a0, a1);
        float r1 = rdeg[3 * NA + d];
        float2 o;
        o.x = a0 * r1 + b1[col];
        o.y = a1 * r1 + b1[col + 1];
        *(float2*)(out + (size_t)(NA + d) * DD + col) = o;
    }
}

extern "C" void kernel_launch(void* const* d_in, const int* in_sizes, int n_in,
                              void* d_out, int out_size, void* d_ws, size_t ws_size,
                              hipStream_t stream) {
    const float* hA = (const float*)d_in[0];
    const float* hB = (const float*)d_in[1];
    const float* W0 = (const float*)d_in[2];
    const float* b0 = (const float*)d_in[3];
    const float* W1 = (const float*)d_in[4];
    const float* b1 = (const float*)d_in[5];
    const float* W2 = (const float*)d_in[6];
    const float* b2 = (const float*)d_in[7];
    const int* s0 = (const int*)d_in[8];
    const int* d0 = (const int*)d_in[9];
    const int* s1 = (const int*)d_in[10];
    const int* d1 = (const int*)d_in[11];
    const int* s2 = (const int*)d_in[12];
    const int* d2 = (const int*)d_in[13];
    float* out = (float*)d_out;
    char* ws = (char*)d_ws;

    // ws layout. P (10.88 MB packed) + O (10.88 MB) alias mA0/mA1 (dead before gemm).
    unsigned short* mA0 = (unsigned short*)(ws + 0);          // 12.8 MB
    unsigned short* mA1 = (unsigned short*)(ws + 12800000);   // 12.8 MB
    unsigned short* mB2 = (unsigned short*)(ws + 25600000);   // 5.12 MB
    unsigned short* P16 = (unsigned short*)(ws + 0);          // 10.88 MB packed counts
    unsigned int*   Pd  = (unsigned int*)(ws + 0);            // dword view of P16
    int*   O            = (int*)  (ws + 10880000);            // 10.88 MB din offsets
    unsigned short* Wt  = (unsigned short*)(ws + 30720000);   // 96 KB
    float* rdeg         = (float*)(ws + 30818304);            // 960 KB
    int*   ideg         = (int*)  (ws + 31778304);            // 960 KB
    int*   rp           = (int*)  (ws + 32738304);            // 480 KB
    int*   spart        = (int*)  (ws + 33218304);            // 1 KB
    int*   rank0        = (int*)  (ws + 33219328);            // 2.4 MB
    int*   rank1        = (int*)  (ws + 35619328);            // 1.2 MB
    int*   rank2        = (int*)  (ws + 36819328);            // 1.2 MB
    int*   csr0         = (int*)  (ws + 38019328);            // 2.4 MB
    int*   csr1         = (int*)  (ws + 40419328);            // 1.2 MB
    int*   csr2         = (int*)  (ws + 41619328);            // 1.2 MB

    hist_kernel<<<dim3(2, 32, 6), 1024, 0, stream>>>(s0, d0, s1, d1, s2, d2,
                                                     Pd, rank0, rank1, rank2);
    reduce_kernel<<<(DEG_TOT + 255) / 256, 256, 0, stream>>>(P16, ideg, rdeg);

    scan_reduce<<<dim3(49, 3), 256, 0, stream>>>(ideg, spart);
    spine_kernel<<<1, 192, 0, stream>>>(spart);
    scan_final<<<dim3(49, 3), 256, 0, stream>>>(ideg, spart, rp);

    offsets_kernel<<<(2 * NA + NB + 255) / 256, 256, 0, stream>>>(P16, rp, O);
    place_parallel<<<dim3((NE0 + 511) / 512, 1, 3), 512, 0, stream>>>(
        s0, d0, s1, d1, s2, d2, O, rank0, rank1, rank2, csr0, csr1, csr2);

    wt_kernel<<<(3 * DD * DD + 255) / 256, 256, 0, stream>>>(W0, W1, W2, Wt);
    gemm_all<<<782 + 313, 256, 0, stream>>>(hA, hB, Wt, rdeg, mA0, mA1, mB2);

    gather_all<<<12500 + 5000, 256, 0, stream>>>(mA0, mA1, mB2,
        csr0, csr1, csr2, rp, ideg, rdeg, b0, b1, b2, out);
}